// Round 11
// baseline (195.153 us; speedup 1.0000x reference)
//
#include <hip/hip_runtime.h>

#define NCLS 8
#define NPT  2048
#define DIM  64
#define NROUNDS 11
#define NBLK 512                    // 4 * 16 * NCLS persistent blocks
#define FINF 3.402823466e38f
#define INFK 0xFFFFFFFFu
#define INF64 0xFFFFFFFFFFFFFFFFull

typedef unsigned int u32;
typedef unsigned long long u64;
typedef unsigned short u16;
typedef _Float16 f16_t;
typedef __attribute__((ext_vector_type(8))) f16_t f16x8;
typedef __attribute__((ext_vector_type(4))) float f32x4;
typedef __attribute__((ext_vector_type(4))) u32 u32x4;

#define MFMAH(a, b, c) __builtin_amdgcn_mfma_f32_16x16x32_f16((a), (b), (c), 0, 0, 0)

#define ALOAD_U64(p) __hip_atomic_load((p), __ATOMIC_RELAXED, __HIP_MEMORY_SCOPE_AGENT)
#define ALOAD_U32(p) __hip_atomic_load((p), __ATOMIC_RELAXED, __HIP_MEMORY_SCOPE_AGENT)
#define ALOAD_F32(p) __hip_atomic_load((p), __ATOMIC_RELAXED, __HIP_MEMORY_SCOPE_AGENT)
#define ASTORE_U32(p, v) __hip_atomic_store((p), (v), __ATOMIC_RELAXED, __HIP_MEMORY_SCOPE_AGENT)
#define ASTORE_F32(p, v) __hip_atomic_store((p), (v), __ATOMIC_RELAXED, __HIP_MEMORY_SCOPE_AGENT)

// ---------------------------------------------------------------------------
// Atomic-only grid barrier (rounds 9/10 lesson: fences cost ~60us on
// multi-XCD CDNA; atomics at the coherent point are cheap). The leading
// __syncthreads drains every wave's vmcnt -> all this block's global atomics
// are complete before the arrive. Counter per barrier INSTANCE (no reuse).
// Requires all NBLK blocks co-resident -> cooperative launch + host check.
// ---------------------------------------------------------------------------
__device__ __forceinline__ void gbar(u32* __restrict__ ctr, int inst) {
    __syncthreads();
    if (threadIdx.x == 0) {
        __hip_atomic_fetch_add(&ctr[inst], 1u, __ATOMIC_RELAXED,
                               __HIP_MEMORY_SCOPE_AGENT);
        while (ALOAD_U32(&ctr[inst]) < NBLK) __builtin_amdgcn_s_sleep(8);
    }
    __syncthreads();
}

// ---------------------------------------------------------------------------
// Kernel 1: fp32 -> fp16 convert + exact fp32 row norms + ALL state init.
// Separate dispatch so xh/sq are read-only for the persistent kernel
// (kernel boundary = coherence; avoids round-8's phase-0 plain-store hazard).
// ---------------------------------------------------------------------------
__global__ void convinit_kernel(const float* __restrict__ x, u16* __restrict__ xh,
                                float* __restrict__ sq, u32* __restrict__ comp,
                                u64* __restrict__ minEdge, float* __restrict__ lossAcc,
                                u32* __restrict__ done, u32* __restrict__ counters) {
    int row  = blockIdx.x * 4 + (threadIdx.x >> 6);
    int lane = threadIdx.x & 63;
    size_t idx = (size_t)row * DIM + lane;
    float v = x[idx];
    xh[idx] = __builtin_bit_cast(u16, (f16_t)v);   // RNE
    float s = v * v;
    #pragma unroll
    for (int m = 32; m >= 1; m >>= 1) s += __shfl_xor(s, m);
    if (lane == 0) {
        sq[row]   = s;
        comp[row] = (u32)(row & (NPT - 1));        // fallback path state
        if (row < NCLS) { lossAcc[row] = 0.0f; done[row] = 0u; }
    }
    int g = blockIdx.x * 256 + threadIdx.x;
    if (g < 2 * NCLS * NPT) minEdge[g] = INF64;    // both round-parity buffers
    if (g < NROUNDS * NCLS + NROUNDS + 1) counters[g] = 0u;  // both schemes
}

// ---------------------------------------------------------------------------
// Kernel 2 (primary): persistent cooperative Boruvka. One dispatch runs all
// rounds. Per round: scan (single-pass fp16 MFMA Gram, bitwise-symmetric ->
// exact mutual-edge dedup; LDS per-comp pre-reduction; atomicMin to the
// rnd-parity minEdge buffer with DECREASING round tag) -> gbar -> uniform
// all-done check -> redundant per-block merge (comp lives ONLY in LDS).
// Cross-block traffic is atomics-only; zero fences anywhere.
// ---------------------------------------------------------------------------
__global__ __launch_bounds__(256) void persist_kernel(
    const u16* __restrict__ xh, const float* __restrict__ sq,
    u64* __restrict__ minEdge, float* __restrict__ lossAcc,
    u32* __restrict__ doneG, u32* __restrict__ counters, float* __restrict__ out)
{
    __shared__ u16   compL[NPT];                          // 4 KB persistent
    __shared__ float sqC[512];                            // 2 KB persistent
    __shared__ __align__(16) char uni[NPT * 8 + NPT * 2]; // 20 KB union
    __shared__ float rwS[4];
    __shared__ u32   rcS[4];
    __shared__ u32   shRoot, shConv, shDone;

    u64* minT    = (u64*)uni;               // scan:  per-component table
    u64* edgeL   = (u64*)uni;               // merge: edge copy (same region)
    u16* parentL = (u16*)(uni + NPT * 8);   // merge: hook forest

    const int c    = blockIdx.z;
    const int rb   = blockIdx.y;            // row block (128 rows)
    const int cs   = blockIdx.x;            // col split (512 cols)
    const int tid  = threadIdx.x;
    const int lane = tid & 63;
    const int w    = tid >> 6;
    const int b    = (c * 16 + rb) * 4 + cs;

    const size_t xbase = (size_t)c * NPT * DIM;
    sqC[tid]       = sq[(size_t)c * NPT + cs * 512 + tid];
    sqC[tid + 256] = sq[(size_t)c * NPT + cs * 512 + 256 + tid];
    #pragma unroll
    for (int k = 0; k < 8; ++k) compL[k * 256 + tid] = (u16)(k * 256 + tid);

    const int kq   = (lane >> 4) * 8;
    const int arow = rb * 128 + w * 32 + (lane & 15);
    f16x8 Ah[2][2];
    #pragma unroll
    for (int rt = 0; rt < 2; ++rt)
        #pragma unroll
        for (int kk = 0; kk < 2; ++kk) {
            size_t off = xbase + (size_t)(arow + rt * 16) * DIM + kk * 32 + kq;
            Ah[rt][kk] = __builtin_bit_cast(f16x8, *(const u32x4*)(xh + off));
        }
    int   rowg_[2][4];
    float sqrow[2][4];
    #pragma unroll
    for (int rt = 0; rt < 2; ++rt)
        #pragma unroll
        for (int r = 0; r < 4; ++r) {
            int rg = rb * 128 + w * 32 + rt * 16 + ((lane >> 4) << 2) + r;
            rowg_[rt][r] = rg;
            sqrow[rt][r] = sq[(size_t)c * NPT + rg];
        }

    bool  mydone    = false;
    float classLoss = 0.0f;
    __syncthreads();

    for (int rnd = 0; rnd < NROUNDS; ++rnd) {
        u64* edgeGb = minEdge + ((size_t)(rnd & 1) * NCLS + c) * NPT;

        if (!mydone) {
            // --- scan ---
            #pragma unroll
            for (int k = 0; k < 8; ++k) minT[k * 256 + tid] = INF64;
            __syncthreads();

            u32 crow[2][4];
            #pragma unroll
            for (int rt = 0; rt < 2; ++rt)
                #pragma unroll
                for (int r = 0; r < 4; ++r) crow[rt][r] = compL[rowg_[rt][r]];

            u32 rm[2][4];
            #pragma unroll
            for (int rt = 0; rt < 2; ++rt)
                #pragma unroll
                for (int r = 0; r < 4; ++r) rm[rt][r] = INFK;

            #pragma unroll 2
            for (int ct = 0; ct < 32; ++ct) {
                const int colb = cs * 512 + ct * 16 + (lane & 15);
                f16x8 Bh[2];
                #pragma unroll
                for (int kk = 0; kk < 2; ++kk) {
                    size_t off = xbase + (size_t)colb * DIM + kk * 32 + kq;
                    Bh[kk] = __builtin_bit_cast(f16x8, *(const u32x4*)(xh + off));
                }
                u32   ccol = compL[colb];
                float sqc_ = sqC[ct * 16 + (lane & 15)];

                #pragma unroll
                for (int rt = 0; rt < 2; ++rt) {
                    f32x4 acc = {0.f, 0.f, 0.f, 0.f};
                    acc = MFMAH(Ah[rt][0], Bh[0], acc);
                    acc = MFMAH(Ah[rt][1], Bh[1], acc);
                    #pragma unroll
                    for (int r = 0; r < 4; ++r) {
                        float d2 = fmaf(-2.0f, acc[r], sqrow[rt][r] + sqc_);
                        d2 = fmaxf(d2, 0.0f);
                        u32 bk = (__float_as_uint(d2) + 0x400u) & 0xFFFFF800u;
                        u32 k2 = bk | (u32)colb;
                        k2 = (crow[rt][r] == ccol) ? INFK : k2;   // masks self
                        rm[rt][r] = min(rm[rt][r], k2);
                    }
                }
            }

            const u64 tagbits = (u64)(15 - rnd) << 60;   // decreasing: new wins
            #pragma unroll
            for (int rt = 0; rt < 2; ++rt)
                #pragma unroll
                for (int r = 0; r < 4; ++r) {
                    u32 bv = rm[rt][r];
                    #pragma unroll
                    for (int m = 8; m >= 1; m >>= 1)
                        bv = min(bv, (u32)__shfl_xor((int)bv, m));
                    if ((lane & 15) == 0 && bv != INFK) {
                        int rowg = rowg_[rt][r];
                        int colg = (int)(bv & 0x7FFu);
                        u32 d21  = bv >> 11;
                        int mn = rowg < colg ? rowg : colg;
                        int mx = rowg < colg ? colg : rowg;
                        u64 key = tagbits | ((u64)d21 << 22) | ((u64)mn << 11) | (u64)mx;
                        atomicMin(&minT[crow[rt][r]], key);
                    }
                }
            __syncthreads();

            #pragma unroll
            for (int k = 0; k < 8; ++k) {
                int i = k * 256 + tid;
                u64 e = minT[i];
                if (e != INF64) atomicMin(&edgeGb[i], e);
            }
        }

        gbar(counters, rnd);   // leading syncthreads drains our atomicMins

        // uniform all-done check: done[] stores happened before their owners'
        // arrive at THIS barrier -> every block reads identical values.
        if (tid == 0) {
            u32 alld = 1;
            #pragma unroll
            for (int cc = 0; cc < NCLS; ++cc) alld &= (ALOAD_U32(&doneG[cc]) != 0u);
            shDone = alld;
        }
        __syncthreads();
        if (shDone) break;

        if (!mydone) {
            // --- merge (redundant, identical in all 64 blocks of class c) ---
            #pragma unroll
            for (int k = 0; k < 8; ++k) {
                int i = k * 256 + tid;
                edgeL[i]   = ALOAD_U64(&edgeGb[i]);
                parentL[i] = (u16)i;
            }
            __syncthreads();

            const u64 T = (u64)(15 - rnd);
            float myw = 0.0f;
            u32   mycnt = 0;
            #pragma unroll
            for (int k = 0; k < 8; ++k) {
                int L = k * 256 + tid;
                u64 e = edgeL[L];
                if (e != INF64 && (e >> 60) == T) {
                    int mn = (int)((e >> 11) & 0x7FF);
                    int mx = (int)(e & 0x7FF);
                    u32 A = compL[mn], B = compL[mx];
                    u32 O = (A == (u32)L) ? B : A;
                    bool mutual = (edgeL[O] == e);
                    if (!(mutual && (u32)L > O)) {
                        parentL[L] = (u16)O;
                        float d2 = __uint_as_float(((u32)(e >> 22) & 0x1FFFFFu) << 11);
                        myw += fabsf(sqrtf(d2) - 1.0f);
                        ++mycnt;
                    }
                }
            }
            __syncthreads();

            // safety: break any residual 2-cycle
            #pragma unroll
            for (int k = 0; k < 8; ++k) {
                int L = k * 256 + tid;
                u32 p1 = parentL[L];
                if (p1 != (u32)L && parentL[p1] == (u32)L && (u32)L > p1)
                    parentL[L] = (u16)L;
            }
            __syncthreads();

            // pointer jumping: 11 doublings
            for (int it = 0; it < 11; ++it) {
                u16 np[8];
                #pragma unroll
                for (int k = 0; k < 8; ++k) {
                    int L = k * 256 + tid;
                    np[k] = parentL[parentL[L]];
                }
                __syncthreads();
                #pragma unroll
                for (int k = 0; k < 8; ++k) parentL[k * 256 + tid] = np[k];
                __syncthreads();
            }

            // new comp (LDS only) + convergence + loss reduction
            u16 nc[8];
            #pragma unroll
            for (int k = 0; k < 8; ++k) nc[k] = parentL[compL[k * 256 + tid]];
            if (tid == 0) { shRoot = nc[0]; shConv = 1; }
            __syncthreads();
            u32 bad = 0;
            #pragma unroll
            for (int k = 0; k < 8; ++k) {
                compL[k * 256 + tid] = nc[k];
                bad |= (u32)(nc[k] != (u16)shRoot);
            }
            if (bad) shConv = 0;   // benign race: all writers write 0

            #pragma unroll
            for (int m = 32; m >= 1; m >>= 1) {
                myw   += __shfl_xor(myw, m);
                mycnt += (u32)__shfl_xor((int)mycnt, m);
            }
            if (lane == 0) { rwS[w] = myw; rcS[w] = mycnt; }
            __syncthreads();

            float rwTot = rwS[0] + rwS[1] + rwS[2] + rwS[3];
            u32   rcTot = rcS[0] + rcS[1] + rcS[2] + rcS[3];
            classLoss += rwTot;
            if (shConv != 0u || rcTot == 0u) {
                mydone = true;
                if (rb == 0 && cs == 0 && tid == 0) ASTORE_U32(&doneG[c], 1u);
            }
        }
    }

    if (rb == 0 && cs == 0 && tid == 0) ASTORE_F32(&lossAcc[c], classLoss);
    gbar(counters, NROUNDS);
    if (b == 0 && tid == 0) {
        float s = 0.0f;
        for (int cc = 0; cc < NCLS; ++cc) s += ALOAD_F32(&lossAcc[cc]);
        out[0] = s * (1.0f / (float)(NPT - 1));
    }
}

// ===========================================================================
// Fallback path: proven round-10 pipeline (149 us) — used if the cooperative
// co-residency check fails.
// ===========================================================================
__global__ __launch_bounds__(256) void scanmerge_kernel(
    const u16* __restrict__ xh, const float* __restrict__ sq,
    u32* __restrict__ comp, u64* __restrict__ minEdge,
    float* __restrict__ lossAcc, u32* __restrict__ classDone,
    u32* __restrict__ counters, int rnd)
{
    const int c = blockIdx.z;
    if (classDone[c]) return;
    const int cs   = blockIdx.x;
    const int rb   = blockIdx.y;
    const int tid  = threadIdx.x;
    const int lane = tid & 63;
    const int w    = tid >> 6;

    __shared__ u32 compL[NPT];
    __shared__ __align__(16) char bufA[NPT * 4];
    __shared__ __align__(16) char bufB[NPT * 8];
    __shared__ float rw[256];
    __shared__ u32   rc[256];
    __shared__ u32   shTicket;
    __shared__ int   conv;

    float* sqL  = (float*)bufA;
    u64*   minT = (u64*)bufB;

    const u32*   compG = comp + (size_t)c * NPT;
    const float* sqG   = sq + (size_t)c * NPT;
    u64*         edgeG = minEdge + (size_t)c * NPT;

    #pragma unroll
    for (int k = 0; k < NPT / 256; ++k) {
        int i = k * 256 + tid;
        compL[i] = compG[i];
        sqL[i]   = sqG[i];
        minT[i]  = INF64;
    }
    __syncthreads();

    const size_t xbase = (size_t)c * NPT * DIM;
    const int    kq    = (lane >> 4) * 8;
    const int    arow  = rb * 128 + w * 32 + (lane & 15);

    f16x8 Ah[2][2];
    #pragma unroll
    for (int rt = 0; rt < 2; ++rt)
        #pragma unroll
        for (int kk = 0; kk < 2; ++kk) {
            size_t off = xbase + (size_t)(arow + rt * 16) * DIM + kk * 32 + kq;
            Ah[rt][kk] = __builtin_bit_cast(f16x8, *(const u32x4*)(xh + off));
        }

    int   rowg_[2][4];
    float sqrow[2][4];
    u32   crow[2][4];
    #pragma unroll
    for (int rt = 0; rt < 2; ++rt)
        #pragma unroll
        for (int r = 0; r < 4; ++r) {
            int rg = rb * 128 + w * 32 + rt * 16 + ((lane >> 4) << 2) + r;
            rowg_[rt][r] = rg;
            sqrow[rt][r] = sqL[rg];
            crow[rt][r]  = compL[rg];
        }

    u32 rm[2][4];
    #pragma unroll
    for (int rt = 0; rt < 2; ++rt)
        #pragma unroll
        for (int r = 0; r < 4; ++r) rm[rt][r] = INFK;

    #pragma unroll 2
    for (int ct = 0; ct < 32; ++ct) {
        const int colb = cs * 512 + ct * 16 + (lane & 15);
        f16x8 Bh[2];
        #pragma unroll
        for (int kk = 0; kk < 2; ++kk) {
            size_t off = xbase + (size_t)colb * DIM + kk * 32 + kq;
            Bh[kk] = __builtin_bit_cast(f16x8, *(const u32x4*)(xh + off));
        }
        u32   ccol = compL[colb];
        float sqc_ = sqL[colb];

        #pragma unroll
        for (int rt = 0; rt < 2; ++rt) {
            f32x4 acc = {0.f, 0.f, 0.f, 0.f};
            acc = MFMAH(Ah[rt][0], Bh[0], acc);
            acc = MFMAH(Ah[rt][1], Bh[1], acc);
            #pragma unroll
            for (int r = 0; r < 4; ++r) {
                float d2 = fmaf(-2.0f, acc[r], sqrow[rt][r] + sqc_);
                d2 = fmaxf(d2, 0.0f);
                u32 bk = (__float_as_uint(d2) + 0x400u) & 0xFFFFF800u;
                u32 k2 = bk | (u32)colb;
                k2 = (crow[rt][r] == ccol) ? INFK : k2;
                rm[rt][r] = min(rm[rt][r], k2);
            }
        }
    }

    #pragma unroll
    for (int rt = 0; rt < 2; ++rt)
        #pragma unroll
        for (int r = 0; r < 4; ++r) {
            u32 bv = rm[rt][r];
            #pragma unroll
            for (int m = 8; m >= 1; m >>= 1)
                bv = min(bv, (u32)__shfl_xor((int)bv, m));
            if ((lane & 15) == 0 && bv != INFK) {
                int rowg = rowg_[rt][r];
                int colg = (int)(bv & 0x7FFu);
                u32 d21  = bv >> 11;
                int mn = rowg < colg ? rowg : colg;
                int mx = rowg < colg ? colg : rowg;
                u64 key = ((u64)d21 << 22) | ((u64)mn << 11) | (u64)mx;
                atomicMin(&minT[crow[rt][r]], key);
            }
        }
    __syncthreads();

    #pragma unroll
    for (int k = 0; k < NPT / 256; ++k) {
        int i = k * 256 + tid;
        u64 e = minT[i];
        if (e != INF64) atomicMin(&edgeG[i], e);
    }

    __syncthreads();
    if (tid == 0)
        shTicket = __hip_atomic_fetch_add(&counters[NROUNDS + 1 + rnd * NCLS + c], 1u,
                                          __ATOMIC_RELAXED, __HIP_MEMORY_SCOPE_AGENT);
    __syncthreads();
    if (shTicket != 63u) return;

    u32* parentL = (u32*)bufA;
    u64* edgeL   = (u64*)bufB;
    u32* compGm  = comp + (size_t)c * NPT;

    #pragma unroll
    for (int k = 0; k < NPT / 256; ++k) {
        int i = k * 256 + tid;
        edgeL[i]   = ALOAD_U64(&edgeG[i]);
        parentL[i] = (u32)i;
    }
    if (tid == 0) conv = 1;
    __syncthreads();

    float myw = 0.0f;
    int   mycnt = 0;
    #pragma unroll
    for (int k = 0; k < NPT / 256; ++k) {
        int L = k * 256 + tid;
        u64 e = edgeL[L];
        if (e != INF64) {
            int mn = (int)((e >> 11) & 0x7FF);
            int mx = (int)(e & 0x7FF);
            u32 A = compL[mn], B = compL[mx];
            u32 O = (A == (u32)L) ? B : A;
            bool mutual = (edgeL[O] == e);
            if (!(mutual && (u32)L > O)) {
                parentL[L] = O;
                float d2 = __uint_as_float((u32)(e >> 22) << 11);
                myw += fabsf(sqrtf(d2) - 1.0f);
                mycnt += 1;
            }
        }
    }
    __syncthreads();

    #pragma unroll
    for (int k = 0; k < NPT / 256; ++k) {
        int L = k * 256 + tid;
        u32 p1 = parentL[L];
        if (p1 != (u32)L && parentL[p1] == (u32)L && (u32)L > p1) parentL[L] = (u32)L;
    }
    __syncthreads();

    for (int it = 0; it < 11; ++it) {
        u32 np[NPT / 256];
        #pragma unroll
        for (int k = 0; k < NPT / 256; ++k) {
            int L = k * 256 + tid;
            np[k] = parentL[parentL[L]];
        }
        __syncthreads();
        #pragma unroll
        for (int k = 0; k < NPT / 256; ++k) parentL[k * 256 + tid] = np[k];
        __syncthreads();
    }

    u32 root0 = parentL[compL[0]];
    #pragma unroll
    for (int k = 0; k < NPT / 256; ++k) {
        int v = k * 256 + tid;
        u32 nc = parentL[compL[v]];
        compGm[v] = nc;
        if (nc != root0) conv = 0;
        edgeG[v] = INF64;
    }

    rw[tid] = myw; rc[tid] = (u32)mycnt;
    __syncthreads();
    for (int s = 128; s >= 1; s >>= 1) {
        if (tid < s) { rw[tid] += rw[tid + s]; rc[tid] += rc[tid + s]; }
        __syncthreads();
    }
    if (tid == 0) {
        lossAcc[c] += rw[0];
        if (conv || rc[0] == 0u) classDone[c] = 1u;
    }
}

__global__ void final2_kernel(const float* __restrict__ lossAcc, float* __restrict__ out) {
    if (threadIdx.x == 0 && blockIdx.x == 0) {
        float s = 0.0f;
        for (int cc = 0; cc < NCLS; ++cc) s += lossAcc[cc] * (1.0f / (float)(NPT - 1));
        out[0] = s;
    }
}

extern "C" void kernel_launch(void* const* d_in, const int* in_sizes, int n_in,
                              void* d_out, int out_size, void* d_ws, size_t ws_size,
                              hipStream_t stream) {
    const float* x   = (const float*)d_in[0];
    float*       out = (float*)d_out;

    const size_t nv = (size_t)NCLS * NPT;
    const size_t nx = (size_t)NCLS * NPT * DIM;
    const size_t ncnt = NROUNDS * NCLS + NROUNDS + 1;   // persist(12) + fallback(88)

    const size_t off_me   = 0;                                  // 2 bufs, u64
    const size_t off_sq   = off_me + 2 * nv * sizeof(u64);
    const size_t off_comp = off_sq + nv * sizeof(float);
    const size_t off_loss = off_comp + nv * sizeof(u32);
    const size_t off_done = off_loss + NCLS * sizeof(float);
    const size_t off_cnt  = off_done + NCLS * sizeof(u32);
    const size_t off_xh   = off_cnt + ((ncnt + 7) & ~7ull) * sizeof(u32);
    const size_t need     = off_xh + nx * sizeof(u16);

    if (ws_size < need) return;   // ws is known-large in this harness

    u64*   minEdge  = (u64*)((char*)d_ws + off_me);
    float* sq       = (float*)((char*)d_ws + off_sq);
    u32*   comp     = (u32*)((char*)d_ws + off_comp);
    float* lossAcc  = (float*)((char*)d_ws + off_loss);
    u32*   done     = (u32*)((char*)d_ws + off_done);
    u32*   counters = (u32*)((char*)d_ws + off_cnt);
    u16*   xh       = (u16*)((char*)d_ws + off_xh);

    convinit_kernel<<<(NCLS * NPT) / 4, 256, 0, stream>>>(x, xh, sq, comp,
                                                          minEdge, lossAcc, done,
                                                          counters);

    // Host-side (capture-safe, deterministic) co-residency check — round-6
    // lesson: never coop-launch blind; round-8 proved this check + 26.6 KB
    // LDS launches and runs.
    int dev = 0, cus = 0, maxBlk = 0;
    bool coopOK = (hipGetDevice(&dev) == hipSuccess) &&
                  (hipDeviceGetAttribute(&cus, hipDeviceAttributeMultiprocessorCount,
                                         dev) == hipSuccess) &&
                  (hipOccupancyMaxActiveBlocksPerMultiprocessor(
                       &maxBlk, persist_kernel, 256, 0) == hipSuccess) &&
                  ((long long)maxBlk * cus >= (long long)NBLK);

    if (coopOK) {
        void* args[] = {(void*)&xh, (void*)&sq, (void*)&minEdge,
                        (void*)&lossAcc, (void*)&done, (void*)&counters, (void*)&out};
        hipLaunchCooperativeKernel(reinterpret_cast<void*>(persist_kernel),
                                   dim3(4, 16, NCLS), dim3(256), args, 0, stream);
    } else {
        for (int r = 0; r < NROUNDS; ++r) {
            scanmerge_kernel<<<dim3(4, NPT / 128, NCLS), 256, 0, stream>>>(
                xh, sq, comp, minEdge, lossAcc, done, counters, r);
        }
        final2_kernel<<<1, 64, 0, stream>>>(lossAcc, out);
    }
}

// Round 12
// 136.056 us; speedup vs baseline: 1.4344x; 1.4344x over previous
//
#include <hip/hip_runtime.h>

#define NCLS 8
#define NPT  2048
#define DIM  64
#define NROUNDS 11
#define NBLK 512                    // 4 * 16 * NCLS persistent blocks
#define CBLK 64                     // blocks per class
#define FINF 3.402823466e38f
#define INFK 0xFFFFFFFFu
#define INF64 0xFFFFFFFFFFFFFFFFull

// counters layout (u32): [c*32 + rnd] per-class barriers (8 x 32 = 256),
// [256] finish ticket, [257 .. 257+NROUNDS*NCLS) fallback tickets.
#define CTR_FIN      256
#define CTR_FALLBACK 257
#define NCNT         (CTR_FALLBACK + NROUNDS * NCLS)

typedef unsigned int u32;
typedef unsigned long long u64;
typedef unsigned short u16;
typedef _Float16 f16_t;
typedef __attribute__((ext_vector_type(8))) f16_t f16x8;
typedef __attribute__((ext_vector_type(4))) float f32x4;
typedef __attribute__((ext_vector_type(4))) u32 u32x4;

#define MFMAH(a, b, c) __builtin_amdgcn_mfma_f32_16x16x32_f16((a), (b), (c), 0, 0, 0)

#define ALOAD_U64(p) __hip_atomic_load((p), __ATOMIC_RELAXED, __HIP_MEMORY_SCOPE_AGENT)
#define ALOAD_U32(p) __hip_atomic_load((p), __ATOMIC_RELAXED, __HIP_MEMORY_SCOPE_AGENT)
#define ALOAD_F32(p) __hip_atomic_load((p), __ATOMIC_RELAXED, __HIP_MEMORY_SCOPE_AGENT)
#define ASTORE_F32(p, v) __hip_atomic_store((p), (v), __ATOMIC_RELAXED, __HIP_MEMORY_SCOPE_AGENT)

// ---------------------------------------------------------------------------
// Per-CLASS atomic barrier (round-11 lesson: one global counter = 512-poller
// line contention ~8us/round; per-class lines have 64 pollers, 8 lines).
// Leading __syncthreads drains every wave's vmcnt -> this block's global
// atomicMins are complete before the arrive. One counter per (class, round),
// never reused. Requires all blocks co-resident (cooperative launch).
// ---------------------------------------------------------------------------
__device__ __forceinline__ void cbar(u32* __restrict__ ctr, int c, int inst) {
    __syncthreads();
    if (threadIdx.x == 0) {
        u32* a = &ctr[c * 32 + inst];
        __hip_atomic_fetch_add(a, 1u, __ATOMIC_RELAXED, __HIP_MEMORY_SCOPE_AGENT);
        while (ALOAD_U32(a) < CBLK) __builtin_amdgcn_s_sleep(1);
    }
    __syncthreads();
}

// ---------------------------------------------------------------------------
// Kernel 1: fp32 -> fp16 convert + exact fp32 row norms + ALL state init.
// ---------------------------------------------------------------------------
__global__ void convinit_kernel(const float* __restrict__ x, u16* __restrict__ xh,
                                float* __restrict__ sq, u32* __restrict__ comp,
                                u64* __restrict__ minEdge, float* __restrict__ lossAcc,
                                u32* __restrict__ done, u32* __restrict__ counters) {
    int row  = blockIdx.x * 4 + (threadIdx.x >> 6);
    int lane = threadIdx.x & 63;
    size_t idx = (size_t)row * DIM + lane;
    float v = x[idx];
    xh[idx] = __builtin_bit_cast(u16, (f16_t)v);   // RNE
    float s = v * v;
    #pragma unroll
    for (int m = 32; m >= 1; m >>= 1) s += __shfl_xor(s, m);
    if (lane == 0) {
        sq[row]   = s;
        comp[row] = (u32)(row & (NPT - 1));        // fallback path state
        if (row < NCLS) { lossAcc[row] = 0.0f; done[row] = 0u; }
    }
    int g = blockIdx.x * 256 + threadIdx.x;
    if (g < 2 * NCLS * NPT) minEdge[g] = INF64;    // both round-parity buffers
    if (g < NCNT) counters[g] = 0u;
}

// ---------------------------------------------------------------------------
// Kernel 2 (primary): persistent cooperative Boruvka, per-class independent.
// Per round: scan (single-pass fp16 MFMA Gram, bitwise-symmetric -> exact
// mutual-edge dedup; LDS per-comp pre-reduction; atomicMin into rnd-parity
// minEdge buffer with DECREASING round tag) -> per-class cbar -> redundant
// all-LDS merge (identical in all 64 blocks). Converged class EXITS (no dead
// rounds, no global sync). Finish: leader ASTOREs loss -> syncthreads drains
// -> relaxed finish ticket; 8th finisher does the fixed-order sum.
// Atomics-only cross-block traffic; zero fences (rounds 9/10 lesson).
// ---------------------------------------------------------------------------
__global__ __launch_bounds__(256) void persist2_kernel(
    const u16* __restrict__ xh, const float* __restrict__ sq,
    u64* __restrict__ minEdge, float* __restrict__ lossAcc,
    u32* __restrict__ counters, float* __restrict__ out)
{
    __shared__ u16   compL[NPT];                          // 4 KB persistent
    __shared__ float sqC[512];                            // 2 KB persistent
    __shared__ __align__(16) char uni[NPT * 8 + NPT * 2]; // 20 KB union
    __shared__ float rwS[4];
    __shared__ u32   rcS[4];
    __shared__ u32   shRoot, shConv;

    u64* minT    = (u64*)uni;               // scan:  per-component table
    u64* edgeL   = (u64*)uni;               // merge: edge copy (same region)
    u16* parentL = (u16*)(uni + NPT * 8);   // merge: hook forest

    const int c    = blockIdx.z;
    const int rb   = blockIdx.y;            // row block (128 rows)
    const int cs   = blockIdx.x;            // col split (512 cols)
    const int tid  = threadIdx.x;
    const int lane = tid & 63;
    const int w    = tid >> 6;
    const bool leader = (rb == 0 && cs == 0);

    const size_t xbase = (size_t)c * NPT * DIM;
    sqC[tid]       = sq[(size_t)c * NPT + cs * 512 + tid];
    sqC[tid + 256] = sq[(size_t)c * NPT + cs * 512 + 256 + tid];
    #pragma unroll
    for (int k = 0; k < 8; ++k) compL[k * 256 + tid] = (u16)(k * 256 + tid);

    const int kq   = (lane >> 4) * 8;
    const int arow = rb * 128 + w * 32 + (lane & 15);
    f16x8 Ah[2][2];
    #pragma unroll
    for (int rt = 0; rt < 2; ++rt)
        #pragma unroll
        for (int kk = 0; kk < 2; ++kk) {
            size_t off = xbase + (size_t)(arow + rt * 16) * DIM + kk * 32 + kq;
            Ah[rt][kk] = __builtin_bit_cast(f16x8, *(const u32x4*)(xh + off));
        }
    int   rowg_[2][4];
    float sqrow[2][4];
    #pragma unroll
    for (int rt = 0; rt < 2; ++rt)
        #pragma unroll
        for (int r = 0; r < 4; ++r) {
            int rg = rb * 128 + w * 32 + rt * 16 + ((lane >> 4) << 2) + r;
            rowg_[rt][r] = rg;
            sqrow[rt][r] = sq[(size_t)c * NPT + rg];
        }

    float classLoss = 0.0f;
    __syncthreads();

    for (int rnd = 0; rnd < NROUNDS; ++rnd) {
        u64* edgeGb = minEdge + ((size_t)(rnd & 1) * NCLS + c) * NPT;

        // --- scan ---
        #pragma unroll
        for (int k = 0; k < 8; ++k) minT[k * 256 + tid] = INF64;
        __syncthreads();

        u32 crow[2][4];
        #pragma unroll
        for (int rt = 0; rt < 2; ++rt)
            #pragma unroll
            for (int r = 0; r < 4; ++r) crow[rt][r] = compL[rowg_[rt][r]];

        u32 rm[2][4];
        #pragma unroll
        for (int rt = 0; rt < 2; ++rt)
            #pragma unroll
            for (int r = 0; r < 4; ++r) rm[rt][r] = INFK;

        #pragma unroll 2
        for (int ct = 0; ct < 32; ++ct) {
            const int colb = cs * 512 + ct * 16 + (lane & 15);
            f16x8 Bh[2];
            #pragma unroll
            for (int kk = 0; kk < 2; ++kk) {
                size_t off = xbase + (size_t)colb * DIM + kk * 32 + kq;
                Bh[kk] = __builtin_bit_cast(f16x8, *(const u32x4*)(xh + off));
            }
            u32   ccol = compL[colb];
            float sqc_ = sqC[ct * 16 + (lane & 15)];

            #pragma unroll
            for (int rt = 0; rt < 2; ++rt) {
                f32x4 acc = {0.f, 0.f, 0.f, 0.f};
                acc = MFMAH(Ah[rt][0], Bh[0], acc);
                acc = MFMAH(Ah[rt][1], Bh[1], acc);
                #pragma unroll
                for (int r = 0; r < 4; ++r) {
                    float d2 = fmaf(-2.0f, acc[r], sqrow[rt][r] + sqc_);
                    d2 = fmaxf(d2, 0.0f);
                    u32 bk = (__float_as_uint(d2) + 0x400u) & 0xFFFFF800u;
                    u32 k2 = bk | (u32)colb;
                    k2 = (crow[rt][r] == ccol) ? INFK : k2;   // masks self
                    rm[rt][r] = min(rm[rt][r], k2);
                }
            }
        }

        const u64 tagbits = (u64)(15 - rnd) << 60;   // decreasing: new wins
        #pragma unroll
        for (int rt = 0; rt < 2; ++rt)
            #pragma unroll
            for (int r = 0; r < 4; ++r) {
                u32 bv = rm[rt][r];
                #pragma unroll
                for (int m = 8; m >= 1; m >>= 1)
                    bv = min(bv, (u32)__shfl_xor((int)bv, m));
                if ((lane & 15) == 0 && bv != INFK) {
                    int rowg = rowg_[rt][r];
                    int colg = (int)(bv & 0x7FFu);
                    u32 d21  = bv >> 11;
                    int mn = rowg < colg ? rowg : colg;
                    int mx = rowg < colg ? colg : rowg;
                    u64 key = tagbits | ((u64)d21 << 22) | ((u64)mn << 11) | (u64)mx;
                    atomicMin(&minT[crow[rt][r]], key);
                }
            }
        __syncthreads();

        #pragma unroll
        for (int k = 0; k < 8; ++k) {
            int i = k * 256 + tid;
            u64 e = minT[i];
            if (e != INF64) atomicMin(&edgeGb[i], e);
        }

        cbar(counters, c, rnd);   // leading syncthreads drains our atomicMins

        // --- merge (redundant, identical in all 64 blocks of class c) ---
        #pragma unroll
        for (int k = 0; k < 8; ++k) {
            int i = k * 256 + tid;
            edgeL[i]   = ALOAD_U64(&edgeGb[i]);
            parentL[i] = (u16)i;
        }
        __syncthreads();

        const u64 T = (u64)(15 - rnd);
        float myw = 0.0f;
        u32   mycnt = 0;
        #pragma unroll
        for (int k = 0; k < 8; ++k) {
            int L = k * 256 + tid;
            u64 e = edgeL[L];
            if (e != INF64 && (e >> 60) == T) {
                int mn = (int)((e >> 11) & 0x7FF);
                int mx = (int)(e & 0x7FF);
                u32 A = compL[mn], B = compL[mx];
                u32 O = (A == (u32)L) ? B : A;
                bool mutual = (edgeL[O] == e);
                if (!(mutual && (u32)L > O)) {
                    parentL[L] = (u16)O;
                    float d2 = __uint_as_float(((u32)(e >> 22) & 0x1FFFFFu) << 11);
                    myw += fabsf(sqrtf(d2) - 1.0f);
                    ++mycnt;
                }
            }
        }
        __syncthreads();

        // safety: break any residual 2-cycle
        #pragma unroll
        for (int k = 0; k < 8; ++k) {
            int L = k * 256 + tid;
            u32 p1 = parentL[L];
            if (p1 != (u32)L && parentL[p1] == (u32)L && (u32)L > p1)
                parentL[L] = (u16)L;
        }
        __syncthreads();

        // pointer jumping: 11 doublings
        for (int it = 0; it < 11; ++it) {
            u16 np[8];
            #pragma unroll
            for (int k = 0; k < 8; ++k) {
                int L = k * 256 + tid;
                np[k] = parentL[parentL[L]];
            }
            __syncthreads();
            #pragma unroll
            for (int k = 0; k < 8; ++k) parentL[k * 256 + tid] = np[k];
            __syncthreads();
        }

        // new comp (LDS only) + convergence + loss reduction
        u16 nc[8];
        #pragma unroll
        for (int k = 0; k < 8; ++k) nc[k] = parentL[compL[k * 256 + tid]];
        if (tid == 0) { shRoot = nc[0]; shConv = 1; }
        __syncthreads();
        u32 bad = 0;
        #pragma unroll
        for (int k = 0; k < 8; ++k) {
            compL[k * 256 + tid] = nc[k];
            bad |= (u32)(nc[k] != (u16)shRoot);
        }
        if (bad) shConv = 0;   // benign race: all writers write 0

        #pragma unroll
        for (int m = 32; m >= 1; m >>= 1) {
            myw   += __shfl_xor(myw, m);
            mycnt += (u32)__shfl_xor((int)mycnt, m);
        }
        if (lane == 0) { rwS[w] = myw; rcS[w] = mycnt; }
        __syncthreads();

        classLoss += rwS[0] + rwS[1] + rwS[2] + rwS[3];
        u32 rcTot  = rcS[0] + rcS[1] + rcS[2] + rcS[3];
        if (shConv != 0u || rcTot == 0u) break;   // identical in all 64 blocks
    }

    // ---- finish: leader publishes loss; 8th finisher sums (fixed order) ----
    if (leader && tid == 0) ASTORE_F32(&lossAcc[c], classLoss);
    __syncthreads();            // drains the ASTORE before the ticket
    if (leader && tid == 0) {
        u32 t = __hip_atomic_fetch_add(&counters[CTR_FIN], 1u,
                                       __ATOMIC_RELAXED, __HIP_MEMORY_SCOPE_AGENT);
        if (t == NCLS - 1) {
            float s = 0.0f;
            for (int cc = 0; cc < NCLS; ++cc) s += ALOAD_F32(&lossAcc[cc]);
            out[0] = s * (1.0f / (float)(NPT - 1));
        }
    }
}

// ===========================================================================
// Fallback path: proven round-10 pipeline (149 us) — used if the cooperative
// co-residency check fails.
// ===========================================================================
__global__ __launch_bounds__(256) void scanmerge_kernel(
    const u16* __restrict__ xh, const float* __restrict__ sq,
    u32* __restrict__ comp, u64* __restrict__ minEdge,
    float* __restrict__ lossAcc, u32* __restrict__ classDone,
    u32* __restrict__ counters, int rnd)
{
    const int c = blockIdx.z;
    if (classDone[c]) return;
    const int cs   = blockIdx.x;
    const int rb   = blockIdx.y;
    const int tid  = threadIdx.x;
    const int lane = tid & 63;
    const int w    = tid >> 6;

    __shared__ u32 compL[NPT];
    __shared__ __align__(16) char bufA[NPT * 4];
    __shared__ __align__(16) char bufB[NPT * 8];
    __shared__ float rw[256];
    __shared__ u32   rc[256];
    __shared__ u32   shTicket;
    __shared__ int   conv;

    float* sqL  = (float*)bufA;
    u64*   minT = (u64*)bufB;

    const u32*   compG = comp + (size_t)c * NPT;
    const float* sqG   = sq + (size_t)c * NPT;
    u64*         edgeG = minEdge + (size_t)c * NPT;

    #pragma unroll
    for (int k = 0; k < NPT / 256; ++k) {
        int i = k * 256 + tid;
        compL[i] = compG[i];
        sqL[i]   = sqG[i];
        minT[i]  = INF64;
    }
    __syncthreads();

    const size_t xbase = (size_t)c * NPT * DIM;
    const int    kq    = (lane >> 4) * 8;
    const int    arow  = rb * 128 + w * 32 + (lane & 15);

    f16x8 Ah[2][2];
    #pragma unroll
    for (int rt = 0; rt < 2; ++rt)
        #pragma unroll
        for (int kk = 0; kk < 2; ++kk) {
            size_t off = xbase + (size_t)(arow + rt * 16) * DIM + kk * 32 + kq;
            Ah[rt][kk] = __builtin_bit_cast(f16x8, *(const u32x4*)(xh + off));
        }

    int   rowg_[2][4];
    float sqrow[2][4];
    u32   crow[2][4];
    #pragma unroll
    for (int rt = 0; rt < 2; ++rt)
        #pragma unroll
        for (int r = 0; r < 4; ++r) {
            int rg = rb * 128 + w * 32 + rt * 16 + ((lane >> 4) << 2) + r;
            rowg_[rt][r] = rg;
            sqrow[rt][r] = sqL[rg];
            crow[rt][r]  = compL[rg];
        }

    u32 rm[2][4];
    #pragma unroll
    for (int rt = 0; rt < 2; ++rt)
        #pragma unroll
        for (int r = 0; r < 4; ++r) rm[rt][r] = INFK;

    #pragma unroll 2
    for (int ct = 0; ct < 32; ++ct) {
        const int colb = cs * 512 + ct * 16 + (lane & 15);
        f16x8 Bh[2];
        #pragma unroll
        for (int kk = 0; kk < 2; ++kk) {
            size_t off = xbase + (size_t)colb * DIM + kk * 32 + kq;
            Bh[kk] = __builtin_bit_cast(f16x8, *(const u32x4*)(xh + off));
        }
        u32   ccol = compL[colb];
        float sqc_ = sqL[colb];

        #pragma unroll
        for (int rt = 0; rt < 2; ++rt) {
            f32x4 acc = {0.f, 0.f, 0.f, 0.f};
            acc = MFMAH(Ah[rt][0], Bh[0], acc);
            acc = MFMAH(Ah[rt][1], Bh[1], acc);
            #pragma unroll
            for (int r = 0; r < 4; ++r) {
                float d2 = fmaf(-2.0f, acc[r], sqrow[rt][r] + sqc_);
                d2 = fmaxf(d2, 0.0f);
                u32 bk = (__float_as_uint(d2) + 0x400u) & 0xFFFFF800u;
                u32 k2 = bk | (u32)colb;
                k2 = (crow[rt][r] == ccol) ? INFK : k2;
                rm[rt][r] = min(rm[rt][r], k2);
            }
        }
    }

    #pragma unroll
    for (int rt = 0; rt < 2; ++rt)
        #pragma unroll
        for (int r = 0; r < 4; ++r) {
            u32 bv = rm[rt][r];
            #pragma unroll
            for (int m = 8; m >= 1; m >>= 1)
                bv = min(bv, (u32)__shfl_xor((int)bv, m));
            if ((lane & 15) == 0 && bv != INFK) {
                int rowg = rowg_[rt][r];
                int colg = (int)(bv & 0x7FFu);
                u32 d21  = bv >> 11;
                int mn = rowg < colg ? rowg : colg;
                int mx = rowg < colg ? colg : rowg;
                u64 key = ((u64)d21 << 22) | ((u64)mn << 11) | (u64)mx;
                atomicMin(&minT[crow[rt][r]], key);
            }
        }
    __syncthreads();

    #pragma unroll
    for (int k = 0; k < NPT / 256; ++k) {
        int i = k * 256 + tid;
        u64 e = minT[i];
        if (e != INF64) atomicMin(&edgeG[i], e);
    }

    __syncthreads();
    if (tid == 0)
        shTicket = __hip_atomic_fetch_add(&counters[CTR_FALLBACK + rnd * NCLS + c], 1u,
                                          __ATOMIC_RELAXED, __HIP_MEMORY_SCOPE_AGENT);
    __syncthreads();
    if (shTicket != 63u) return;

    u32* parentL = (u32*)bufA;
    u64* edgeL   = (u64*)bufB;
    u32* compGm  = comp + (size_t)c * NPT;

    #pragma unroll
    for (int k = 0; k < NPT / 256; ++k) {
        int i = k * 256 + tid;
        edgeL[i]   = ALOAD_U64(&edgeG[i]);
        parentL[i] = (u32)i;
    }
    if (tid == 0) conv = 1;
    __syncthreads();

    float myw = 0.0f;
    int   mycnt = 0;
    #pragma unroll
    for (int k = 0; k < NPT / 256; ++k) {
        int L = k * 256 + tid;
        u64 e = edgeL[L];
        if (e != INF64) {
            int mn = (int)((e >> 11) & 0x7FF);
            int mx = (int)(e & 0x7FF);
            u32 A = compL[mn], B = compL[mx];
            u32 O = (A == (u32)L) ? B : A;
            bool mutual = (edgeL[O] == e);
            if (!(mutual && (u32)L > O)) {
                parentL[L] = O;
                float d2 = __uint_as_float((u32)(e >> 22) << 11);
                myw += fabsf(sqrtf(d2) - 1.0f);
                mycnt += 1;
            }
        }
    }
    __syncthreads();

    #pragma unroll
    for (int k = 0; k < NPT / 256; ++k) {
        int L = k * 256 + tid;
        u32 p1 = parentL[L];
        if (p1 != (u32)L && parentL[p1] == (u32)L && (u32)L > p1) parentL[L] = (u32)L;
    }
    __syncthreads();

    for (int it = 0; it < 11; ++it) {
        u32 np[NPT / 256];
        #pragma unroll
        for (int k = 0; k < NPT / 256; ++k) {
            int L = k * 256 + tid;
            np[k] = parentL[parentL[L]];
        }
        __syncthreads();
        #pragma unroll
        for (int k = 0; k < NPT / 256; ++k) parentL[k * 256 + tid] = np[k];
        __syncthreads();
    }

    u32 root0 = parentL[compL[0]];
    #pragma unroll
    for (int k = 0; k < NPT / 256; ++k) {
        int v = k * 256 + tid;
        u32 nc = parentL[compL[v]];
        compGm[v] = nc;
        if (nc != root0) conv = 0;
        edgeG[v] = INF64;
    }

    rw[tid] = myw; rc[tid] = (u32)mycnt;
    __syncthreads();
    for (int s = 128; s >= 1; s >>= 1) {
        if (tid < s) { rw[tid] += rw[tid + s]; rc[tid] += rc[tid + s]; }
        __syncthreads();
    }
    if (tid == 0) {
        lossAcc[c] += rw[0];
        if (conv || rc[0] == 0u) classDone[c] = 1u;
    }
}

__global__ void final2_kernel(const float* __restrict__ lossAcc, float* __restrict__ out) {
    if (threadIdx.x == 0 && blockIdx.x == 0) {
        float s = 0.0f;
        for (int cc = 0; cc < NCLS; ++cc) s += lossAcc[cc] * (1.0f / (float)(NPT - 1));
        out[0] = s;
    }
}

extern "C" void kernel_launch(void* const* d_in, const int* in_sizes, int n_in,
                              void* d_out, int out_size, void* d_ws, size_t ws_size,
                              hipStream_t stream) {
    const float* x   = (const float*)d_in[0];
    float*       out = (float*)d_out;

    const size_t nv = (size_t)NCLS * NPT;
    const size_t nx = (size_t)NCLS * NPT * DIM;

    const size_t off_me   = 0;                                  // 2 bufs, u64
    const size_t off_sq   = off_me + 2 * nv * sizeof(u64);
    const size_t off_comp = off_sq + nv * sizeof(float);
    const size_t off_loss = off_comp + nv * sizeof(u32);
    const size_t off_done = off_loss + NCLS * sizeof(float);
    const size_t off_cnt  = off_done + NCLS * sizeof(u32);
    const size_t off_xh   = off_cnt + (((size_t)NCNT + 7) & ~7ull) * sizeof(u32);
    const size_t need     = off_xh + nx * sizeof(u16);

    if (ws_size < need) return;   // ws is known-large in this harness

    u64*   minEdge  = (u64*)((char*)d_ws + off_me);
    float* sq       = (float*)((char*)d_ws + off_sq);
    u32*   comp     = (u32*)((char*)d_ws + off_comp);
    float* lossAcc  = (float*)((char*)d_ws + off_loss);
    u32*   done     = (u32*)((char*)d_ws + off_done);
    u32*   counters = (u32*)((char*)d_ws + off_cnt);
    u16*   xh       = (u16*)((char*)d_ws + off_xh);

    convinit_kernel<<<(NCLS * NPT) / 4, 256, 0, stream>>>(x, xh, sq, comp,
                                                          minEdge, lossAcc, done,
                                                          counters);

    // Host-side (capture-safe, deterministic) co-residency check — round-6
    // lesson: never coop-launch blind.
    int dev = 0, cus = 0, maxBlk = 0;
    bool coopOK = (hipGetDevice(&dev) == hipSuccess) &&
                  (hipDeviceGetAttribute(&cus, hipDeviceAttributeMultiprocessorCount,
                                         dev) == hipSuccess) &&
                  (hipOccupancyMaxActiveBlocksPerMultiprocessor(
                       &maxBlk, persist2_kernel, 256, 0) == hipSuccess) &&
                  ((long long)maxBlk * cus >= (long long)NBLK);

    if (coopOK) {
        void* args[] = {(void*)&xh, (void*)&sq, (void*)&minEdge,
                        (void*)&lossAcc, (void*)&counters, (void*)&out};
        hipLaunchCooperativeKernel(reinterpret_cast<void*>(persist2_kernel),
                                   dim3(4, 16, NCLS), dim3(256), args, 0, stream);
    } else {
        for (int r = 0; r < NROUNDS; ++r) {
            scanmerge_kernel<<<dim3(4, NPT / 128, NCLS), 256, 0, stream>>>(
                xh, sq, comp, minEdge, lossAcc, done, counters, r);
        }
        final2_kernel<<<1, 64, 0, stream>>>(lossAcc, out);
    }
}

// Round 13
// 116.674 us; speedup vs baseline: 1.6726x; 1.1661x over previous
//
#include <hip/hip_runtime.h>

#define NCLS 8
#define NPT  2048
#define DIM  64
#define NROUNDS 11
#define NBLK 256                    // 4 cs * 8 rb * NCLS persistent blocks
#define CBLK 32                     // blocks per class
#define FINF 3.402823466e38f
#define INFK 0xFFFFFFFFu
#define INF64 0xFFFFFFFFFFFFFFFFull

// counters layout (u32): [c*32 + rnd] per-class barriers (8 x 32 = 256),
// [256] finish ticket, [257 ..) fallback tickets.
#define CTR_FIN      256
#define CTR_FALLBACK 257
#define NCNT         (CTR_FALLBACK + NROUNDS * NCLS)

typedef unsigned int u32;
typedef unsigned long long u64;
typedef unsigned short u16;
typedef _Float16 f16_t;
typedef __attribute__((ext_vector_type(8))) f16_t f16x8;
typedef __attribute__((ext_vector_type(4))) float f32x4;
typedef __attribute__((ext_vector_type(4))) u32 u32x4;

#define MFMAH(a, b, c) __builtin_amdgcn_mfma_f32_16x16x32_f16((a), (b), (c), 0, 0, 0)

#define ALOAD_U64(p) __hip_atomic_load((p), __ATOMIC_RELAXED, __HIP_MEMORY_SCOPE_AGENT)
#define ALOAD_U32(p) __hip_atomic_load((p), __ATOMIC_RELAXED, __HIP_MEMORY_SCOPE_AGENT)
#define ALOAD_F32(p) __hip_atomic_load((p), __ATOMIC_RELAXED, __HIP_MEMORY_SCOPE_AGENT)
#define ASTORE_F32(p, v) __hip_atomic_store((p), (v), __ATOMIC_RELAXED, __HIP_MEMORY_SCOPE_AGENT)

// ---------------------------------------------------------------------------
// Per-CLASS atomic barrier (proven round 12). Leading __syncthreads drains
// every wave's vmcnt -> this block's global atomicMins complete before the
// arrive. One counter per (class, round). Cooperative launch co-residency.
// ---------------------------------------------------------------------------
__device__ __forceinline__ void cbar(u32* __restrict__ ctr, int c, int inst) {
    __syncthreads();
    if (threadIdx.x == 0) {
        u32* a = &ctr[c * 32 + inst];
        __hip_atomic_fetch_add(a, 1u, __ATOMIC_RELAXED, __HIP_MEMORY_SCOPE_AGENT);
        while (ALOAD_U32(a) < CBLK) __builtin_amdgcn_s_sleep(1);
    }
    __syncthreads();
}

// ---------------------------------------------------------------------------
// Kernel 1: fp32 -> fp16 convert + exact fp32 row norms + ALL state init.
// ---------------------------------------------------------------------------
__global__ void convinit_kernel(const float* __restrict__ x, u16* __restrict__ xh,
                                float* __restrict__ sq, u32* __restrict__ comp,
                                u64* __restrict__ minEdge, float* __restrict__ lossAcc,
                                u32* __restrict__ done, u32* __restrict__ counters) {
    int row  = blockIdx.x * 4 + (threadIdx.x >> 6);
    int lane = threadIdx.x & 63;
    size_t idx = (size_t)row * DIM + lane;
    float v = x[idx];
    xh[idx] = __builtin_bit_cast(u16, (f16_t)v);   // RNE
    float s = v * v;
    #pragma unroll
    for (int m = 32; m >= 1; m >>= 1) s += __shfl_xor(s, m);
    if (lane == 0) {
        sq[row]   = s;
        comp[row] = (u32)(row & (NPT - 1));        // fallback path state
        if (row < NCLS) { lossAcc[row] = 0.0f; done[row] = 0u; }
    }
    int g = blockIdx.x * 256 + threadIdx.x;
    if (g < 2 * NCLS * NPT) minEdge[g] = INF64;    // both round-parity buffers
    if (g < NCNT) counters[g] = 0u;
}

// ---------------------------------------------------------------------------
// Kernel 2 (primary): persistent cooperative Boruvka, 512-thread blocks,
// 1 block/CU (round-12 lesson: 2 blocks/CU each doing the redundant merge
// doubled per-CU merge work; one 8-wave block halves merge wall-clock).
// Per round: scan (single-pass fp16 MFMA Gram -> bitwise-symmetric exact
// mutual-edge dedup; LDS per-comp pre-reduction; atomicMin into rnd-parity
// minEdge buffer with decreasing round tag) -> per-class cbar -> redundant
// all-LDS merge with ADAPTIVE pointer jumping (convergence test reuses the
// doubling gather; exits at full compression, cap 12). Converged class
// exits entirely. Atomics-only cross-block traffic; zero fences.
// ---------------------------------------------------------------------------
__global__ __launch_bounds__(512) void persist3_kernel(
    const u16* __restrict__ xh, const float* __restrict__ sq,
    u64* __restrict__ minEdge, float* __restrict__ lossAcc,
    u32* __restrict__ counters, float* __restrict__ out)
{
    __shared__ u16   compL[NPT];                          // 4 KB persistent
    __shared__ float sqC[512];                            // 2 KB persistent
    __shared__ __align__(16) char uni[NPT * 8];           // 16 KB: minT | edgeL
    __shared__ u32   parentL[NPT];                        // 8 KB (u32: fewer conflicts)
    __shared__ float rwS[8];
    __shared__ u32   rcS[8];
    __shared__ u32   shRoot, shConv, shChg;

    u64* minT  = (u64*)uni;               // scan:  per-component table
    u64* edgeL = (u64*)uni;               // merge: edge copy (same region)

    const int c    = blockIdx.z;
    const int rb   = blockIdx.y;          // row block (256 rows)
    const int cs   = blockIdx.x;          // col split (512 cols)
    const int tid  = threadIdx.x;
    const int lane = tid & 63;
    const int w    = tid >> 6;            // 8 waves
    const bool leader = (rb == 0 && cs == 0);

    const size_t xbase = (size_t)c * NPT * DIM;
    sqC[tid & 511] = sq[(size_t)c * NPT + cs * 512 + (tid & 511)];
    #pragma unroll
    for (int k = 0; k < 4; ++k) compL[k * 512 + tid] = (u16)(k * 512 + tid);

    const int kq   = (lane >> 4) * 8;
    const int arow = rb * 256 + w * 32 + (lane & 15);
    f16x8 Ah[2][2];
    #pragma unroll
    for (int rt = 0; rt < 2; ++rt)
        #pragma unroll
        for (int kk = 0; kk < 2; ++kk) {
            size_t off = xbase + (size_t)(arow + rt * 16) * DIM + kk * 32 + kq;
            Ah[rt][kk] = __builtin_bit_cast(f16x8, *(const u32x4*)(xh + off));
        }
    int   rowg_[2][4];
    float sqrow[2][4];
    #pragma unroll
    for (int rt = 0; rt < 2; ++rt)
        #pragma unroll
        for (int r = 0; r < 4; ++r) {
            int rg = rb * 256 + w * 32 + rt * 16 + ((lane >> 4) << 2) + r;
            rowg_[rt][r] = rg;
            sqrow[rt][r] = sq[(size_t)c * NPT + rg];
        }

    float classLoss = 0.0f;
    __syncthreads();

    for (int rnd = 0; rnd < NROUNDS; ++rnd) {
        u64* edgeGb = minEdge + ((size_t)(rnd & 1) * NCLS + c) * NPT;

        // --- scan ---
        #pragma unroll
        for (int k = 0; k < 4; ++k) minT[k * 512 + tid] = INF64;
        __syncthreads();

        u32 crow[2][4];
        #pragma unroll
        for (int rt = 0; rt < 2; ++rt)
            #pragma unroll
            for (int r = 0; r < 4; ++r) crow[rt][r] = compL[rowg_[rt][r]];

        u32 rm[2][4];
        #pragma unroll
        for (int rt = 0; rt < 2; ++rt)
            #pragma unroll
            for (int r = 0; r < 4; ++r) rm[rt][r] = INFK;

        #pragma unroll 4
        for (int ct = 0; ct < 32; ++ct) {
            const int colb = cs * 512 + ct * 16 + (lane & 15);
            f16x8 Bh[2];
            #pragma unroll
            for (int kk = 0; kk < 2; ++kk) {
                size_t off = xbase + (size_t)colb * DIM + kk * 32 + kq;
                Bh[kk] = __builtin_bit_cast(f16x8, *(const u32x4*)(xh + off));
            }
            u32   ccol = compL[colb];
            float sqc_ = sqC[ct * 16 + (lane & 15)];

            #pragma unroll
            for (int rt = 0; rt < 2; ++rt) {
                f32x4 acc = {0.f, 0.f, 0.f, 0.f};
                acc = MFMAH(Ah[rt][0], Bh[0], acc);
                acc = MFMAH(Ah[rt][1], Bh[1], acc);
                #pragma unroll
                for (int r = 0; r < 4; ++r) {
                    float d2 = fmaf(-2.0f, acc[r], sqrow[rt][r] + sqc_);
                    d2 = fmaxf(d2, 0.0f);
                    u32 bk = (__float_as_uint(d2) + 0x400u) & 0xFFFFF800u;  // RNE 21-bit
                    u32 k2 = bk | (u32)colb;
                    k2 = (crow[rt][r] == ccol) ? INFK : k2;   // masks self too
                    rm[rt][r] = min(rm[rt][r], k2);
                }
            }
        }

        const u64 tagbits = (u64)(15 - rnd) << 60;   // decreasing: new wins
        #pragma unroll
        for (int rt = 0; rt < 2; ++rt)
            #pragma unroll
            for (int r = 0; r < 4; ++r) {
                u32 bv = rm[rt][r];
                #pragma unroll
                for (int m = 8; m >= 1; m >>= 1)
                    bv = min(bv, (u32)__shfl_xor((int)bv, m));
                if ((lane & 15) == 0 && bv != INFK) {
                    int rowg = rowg_[rt][r];
                    int colg = (int)(bv & 0x7FFu);
                    u32 d21  = bv >> 11;
                    int mn = rowg < colg ? rowg : colg;
                    int mx = rowg < colg ? colg : rowg;
                    u64 key = tagbits | ((u64)d21 << 22) | ((u64)mn << 11) | (u64)mx;
                    atomicMin(&minT[crow[rt][r]], key);
                }
            }
        __syncthreads();

        #pragma unroll
        for (int k = 0; k < 4; ++k) {
            int i = k * 512 + tid;
            u64 e = minT[i];
            if (e != INF64) atomicMin(&edgeGb[i], e);
        }

        cbar(counters, c, rnd);   // leading syncthreads drains our atomicMins

        // --- merge (redundant, identical in all 32 blocks of class c) ---
        #pragma unroll
        for (int k = 0; k < 4; ++k) {
            int i = k * 512 + tid;
            edgeL[i]   = ALOAD_U64(&edgeGb[i]);
            parentL[i] = (u32)i;
        }
        __syncthreads();

        const u64 T = (u64)(15 - rnd);
        float myw = 0.0f;
        u32   mycnt = 0;
        #pragma unroll
        for (int k = 0; k < 4; ++k) {
            int L = k * 512 + tid;
            u64 e = edgeL[L];
            if (e != INF64 && (e >> 60) == T) {
                int mn = (int)((e >> 11) & 0x7FF);
                int mx = (int)(e & 0x7FF);
                u32 A = compL[mn], B = compL[mx];
                u32 O = (A == (u32)L) ? B : A;
                bool mutual = (edgeL[O] == e);
                if (!(mutual && (u32)L > O)) {
                    parentL[L] = O;
                    float d2 = __uint_as_float(((u32)(e >> 22) & 0x1FFFFFu) << 11);
                    myw += fabsf(sqrtf(d2) - 1.0f);
                    ++mycnt;
                }
            }
        }
        __syncthreads();

        // safety: break any residual 2-cycle
        #pragma unroll
        for (int k = 0; k < 4; ++k) {
            int L = k * 512 + tid;
            u32 p1 = parentL[L];
            if (p1 != (u32)L && parentL[p1] == (u32)L && (u32)L > p1)
                parentL[L] = (u32)L;
        }
        __syncthreads();

        // adaptive pointer jumping: doubling gather doubles as convergence
        // test (pp==p for all -> fully compressed). Cap 12 covers depth 2048.
        for (int itj = 0; itj < 12; ++itj) {
            if (tid == 0) shChg = 0u;
            __syncthreads();
            u32 np[4]; u32 ch = 0;
            #pragma unroll
            for (int k = 0; k < 4; ++k) {
                u32 p  = parentL[k * 512 + tid];
                u32 pp = parentL[p];
                np[k] = pp;
                ch |= (u32)(pp != p);
            }
            if (ch) shChg = 1u;   // benign race: all writers write 1
            __syncthreads();
            if (shChg == 0u) break;
            #pragma unroll
            for (int k = 0; k < 4; ++k) parentL[k * 512 + tid] = np[k];
            __syncthreads();
        }

        // new comp (LDS only) + convergence + loss reduction
        u16 nc[4];
        #pragma unroll
        for (int k = 0; k < 4; ++k) nc[k] = (u16)parentL[compL[k * 512 + tid]];
        if (tid == 0) { shRoot = nc[0]; shConv = 1; }
        __syncthreads();
        u32 bad = 0;
        #pragma unroll
        for (int k = 0; k < 4; ++k) {
            compL[k * 512 + tid] = nc[k];
            bad |= (u32)(nc[k] != (u16)shRoot);
        }
        if (bad) shConv = 0;   // benign race: all writers write 0

        #pragma unroll
        for (int m = 32; m >= 1; m >>= 1) {
            myw   += __shfl_xor(myw, m);
            mycnt += (u32)__shfl_xor((int)mycnt, m);
        }
        if (lane == 0) { rwS[w] = myw; rcS[w] = mycnt; }
        __syncthreads();

        float rwTot = 0.0f; u32 rcTot = 0u;
        #pragma unroll
        for (int i = 0; i < 8; ++i) { rwTot += rwS[i]; rcTot += rcS[i]; }
        classLoss += rwTot;
        if (shConv != 0u || rcTot == 0u) break;   // identical in all 32 blocks
    }

    // ---- finish: leader publishes loss; 8th finisher sums (fixed order) ----
    if (leader && tid == 0) ASTORE_F32(&lossAcc[c], classLoss);
    __syncthreads();            // drains the ASTORE before the ticket
    if (leader && tid == 0) {
        u32 t = __hip_atomic_fetch_add(&counters[CTR_FIN], 1u,
                                       __ATOMIC_RELAXED, __HIP_MEMORY_SCOPE_AGENT);
        if (t == NCLS - 1) {
            float s = 0.0f;
            for (int cc = 0; cc < NCLS; ++cc) s += ALOAD_F32(&lossAcc[cc]);
            out[0] = s * (1.0f / (float)(NPT - 1));
        }
    }
}

// ===========================================================================
// Fallback path: proven round-10 pipeline (149 us) — used if the cooperative
// co-residency check fails.
// ===========================================================================
__global__ __launch_bounds__(256) void scanmerge_kernel(
    const u16* __restrict__ xh, const float* __restrict__ sq,
    u32* __restrict__ comp, u64* __restrict__ minEdge,
    float* __restrict__ lossAcc, u32* __restrict__ classDone,
    u32* __restrict__ counters, int rnd)
{
    const int c = blockIdx.z;
    if (classDone[c]) return;
    const int cs   = blockIdx.x;
    const int rb   = blockIdx.y;
    const int tid  = threadIdx.x;
    const int lane = tid & 63;
    const int w    = tid >> 6;

    __shared__ u32 compL[NPT];
    __shared__ __align__(16) char bufA[NPT * 4];
    __shared__ __align__(16) char bufB[NPT * 8];
    __shared__ float rw[256];
    __shared__ u32   rc[256];
    __shared__ u32   shTicket;
    __shared__ int   conv;

    float* sqL  = (float*)bufA;
    u64*   minT = (u64*)bufB;

    const u32*   compG = comp + (size_t)c * NPT;
    const float* sqG   = sq + (size_t)c * NPT;
    u64*         edgeG = minEdge + (size_t)c * NPT;

    #pragma unroll
    for (int k = 0; k < NPT / 256; ++k) {
        int i = k * 256 + tid;
        compL[i] = compG[i];
        sqL[i]   = sqG[i];
        minT[i]  = INF64;
    }
    __syncthreads();

    const size_t xbase = (size_t)c * NPT * DIM;
    const int    kq    = (lane >> 4) * 8;
    const int    arow  = rb * 128 + w * 32 + (lane & 15);

    f16x8 Ah[2][2];
    #pragma unroll
    for (int rt = 0; rt < 2; ++rt)
        #pragma unroll
        for (int kk = 0; kk < 2; ++kk) {
            size_t off = xbase + (size_t)(arow + rt * 16) * DIM + kk * 32 + kq;
            Ah[rt][kk] = __builtin_bit_cast(f16x8, *(const u32x4*)(xh + off));
        }

    int   rowg_[2][4];
    float sqrow[2][4];
    u32   crow[2][4];
    #pragma unroll
    for (int rt = 0; rt < 2; ++rt)
        #pragma unroll
        for (int r = 0; r < 4; ++r) {
            int rg = rb * 128 + w * 32 + rt * 16 + ((lane >> 4) << 2) + r;
            rowg_[rt][r] = rg;
            sqrow[rt][r] = sqL[rg];
            crow[rt][r]  = compL[rg];
        }

    u32 rm[2][4];
    #pragma unroll
    for (int rt = 0; rt < 2; ++rt)
        #pragma unroll
        for (int r = 0; r < 4; ++r) rm[rt][r] = INFK;

    #pragma unroll 2
    for (int ct = 0; ct < 32; ++ct) {
        const int colb = cs * 512 + ct * 16 + (lane & 15);
        f16x8 Bh[2];
        #pragma unroll
        for (int kk = 0; kk < 2; ++kk) {
            size_t off = xbase + (size_t)colb * DIM + kk * 32 + kq;
            Bh[kk] = __builtin_bit_cast(f16x8, *(const u32x4*)(xh + off));
        }
        u32   ccol = compL[colb];
        float sqc_ = sqL[colb];

        #pragma unroll
        for (int rt = 0; rt < 2; ++rt) {
            f32x4 acc = {0.f, 0.f, 0.f, 0.f};
            acc = MFMAH(Ah[rt][0], Bh[0], acc);
            acc = MFMAH(Ah[rt][1], Bh[1], acc);
            #pragma unroll
            for (int r = 0; r < 4; ++r) {
                float d2 = fmaf(-2.0f, acc[r], sqrow[rt][r] + sqc_);
                d2 = fmaxf(d2, 0.0f);
                u32 bk = (__float_as_uint(d2) + 0x400u) & 0xFFFFF800u;
                u32 k2 = bk | (u32)colb;
                k2 = (crow[rt][r] == ccol) ? INFK : k2;
                rm[rt][r] = min(rm[rt][r], k2);
            }
        }
    }

    #pragma unroll
    for (int rt = 0; rt < 2; ++rt)
        #pragma unroll
        for (int r = 0; r < 4; ++r) {
            u32 bv = rm[rt][r];
            #pragma unroll
            for (int m = 8; m >= 1; m >>= 1)
                bv = min(bv, (u32)__shfl_xor((int)bv, m));
            if ((lane & 15) == 0 && bv != INFK) {
                int rowg = rowg_[rt][r];
                int colg = (int)(bv & 0x7FFu);
                u32 d21  = bv >> 11;
                int mn = rowg < colg ? rowg : colg;
                int mx = rowg < colg ? colg : rowg;
                u64 key = ((u64)d21 << 22) | ((u64)mn << 11) | (u64)mx;
                atomicMin(&minT[crow[rt][r]], key);
            }
        }
    __syncthreads();

    #pragma unroll
    for (int k = 0; k < NPT / 256; ++k) {
        int i = k * 256 + tid;
        u64 e = minT[i];
        if (e != INF64) atomicMin(&edgeG[i], e);
    }

    __syncthreads();
    if (tid == 0)
        shTicket = __hip_atomic_fetch_add(&counters[CTR_FALLBACK + rnd * NCLS + c], 1u,
                                          __ATOMIC_RELAXED, __HIP_MEMORY_SCOPE_AGENT);
    __syncthreads();
    if (shTicket != 63u) return;

    u32* parentL = (u32*)bufA;
    u64* edgeL   = (u64*)bufB;
    u32* compGm  = comp + (size_t)c * NPT;

    #pragma unroll
    for (int k = 0; k < NPT / 256; ++k) {
        int i = k * 256 + tid;
        edgeL[i]   = ALOAD_U64(&edgeG[i]);
        parentL[i] = (u32)i;
    }
    if (tid == 0) conv = 1;
    __syncthreads();

    float myw = 0.0f;
    int   mycnt = 0;
    #pragma unroll
    for (int k = 0; k < NPT / 256; ++k) {
        int L = k * 256 + tid;
        u64 e = edgeL[L];
        if (e != INF64) {
            int mn = (int)((e >> 11) & 0x7FF);
            int mx = (int)(e & 0x7FF);
            u32 A = compL[mn], B = compL[mx];
            u32 O = (A == (u32)L) ? B : A;
            bool mutual = (edgeL[O] == e);
            if (!(mutual && (u32)L > O)) {
                parentL[L] = O;
                float d2 = __uint_as_float((u32)(e >> 22) << 11);
                myw += fabsf(sqrtf(d2) - 1.0f);
                mycnt += 1;
            }
        }
    }
    __syncthreads();

    #pragma unroll
    for (int k = 0; k < NPT / 256; ++k) {
        int L = k * 256 + tid;
        u32 p1 = parentL[L];
        if (p1 != (u32)L && parentL[p1] == (u32)L && (u32)L > p1) parentL[L] = (u32)L;
    }
    __syncthreads();

    for (int it = 0; it < 11; ++it) {
        u32 np[NPT / 256];
        #pragma unroll
        for (int k = 0; k < NPT / 256; ++k) {
            int L = k * 256 + tid;
            np[k] = parentL[parentL[L]];
        }
        __syncthreads();
        #pragma unroll
        for (int k = 0; k < NPT / 256; ++k) parentL[k * 256 + tid] = np[k];
        __syncthreads();
    }

    u32 root0 = parentL[compL[0]];
    #pragma unroll
    for (int k = 0; k < NPT / 256; ++k) {
        int v = k * 256 + tid;
        u32 nc = parentL[compL[v]];
        compGm[v] = nc;
        if (nc != root0) conv = 0;
        edgeG[v] = INF64;
    }

    rw[tid] = myw; rc[tid] = (u32)mycnt;
    __syncthreads();
    for (int s = 128; s >= 1; s >>= 1) {
        if (tid < s) { rw[tid] += rw[tid + s]; rc[tid] += rc[tid + s]; }
        __syncthreads();
    }
    if (tid == 0) {
        lossAcc[c] += rw[0];
        if (conv || rc[0] == 0u) classDone[c] = 1u;
    }
}

__global__ void final2_kernel(const float* __restrict__ lossAcc, float* __restrict__ out) {
    if (threadIdx.x == 0 && blockIdx.x == 0) {
        float s = 0.0f;
        for (int cc = 0; cc < NCLS; ++cc) s += lossAcc[cc] * (1.0f / (float)(NPT - 1));
        out[0] = s;
    }
}

extern "C" void kernel_launch(void* const* d_in, const int* in_sizes, int n_in,
                              void* d_out, int out_size, void* d_ws, size_t ws_size,
                              hipStream_t stream) {
    const float* x   = (const float*)d_in[0];
    float*       out = (float*)d_out;

    const size_t nv = (size_t)NCLS * NPT;
    const size_t nx = (size_t)NCLS * NPT * DIM;

    const size_t off_me   = 0;                                  // 2 bufs, u64
    const size_t off_sq   = off_me + 2 * nv * sizeof(u64);
    const size_t off_comp = off_sq + nv * sizeof(float);
    const size_t off_loss = off_comp + nv * sizeof(u32);
    const size_t off_done = off_loss + NCLS * sizeof(float);
    const size_t off_cnt  = off_done + NCLS * sizeof(u32);
    const size_t off_xh   = off_cnt + (((size_t)NCNT + 7) & ~7ull) * sizeof(u32);
    const size_t need     = off_xh + nx * sizeof(u16);

    if (ws_size < need) return;   // ws is known-large in this harness

    u64*   minEdge  = (u64*)((char*)d_ws + off_me);
    float* sq       = (float*)((char*)d_ws + off_sq);
    u32*   comp     = (u32*)((char*)d_ws + off_comp);
    float* lossAcc  = (float*)((char*)d_ws + off_loss);
    u32*   done     = (u32*)((char*)d_ws + off_done);
    u32*   counters = (u32*)((char*)d_ws + off_cnt);
    u16*   xh       = (u16*)((char*)d_ws + off_xh);

    convinit_kernel<<<(NCLS * NPT) / 4, 256, 0, stream>>>(x, xh, sq, comp,
                                                          minEdge, lossAcc, done,
                                                          counters);

    // Host-side (capture-safe, deterministic) co-residency check — round-6
    // lesson: never coop-launch blind.
    int dev = 0, cus = 0, maxBlk = 0;
    bool coopOK = (hipGetDevice(&dev) == hipSuccess) &&
                  (hipDeviceGetAttribute(&cus, hipDeviceAttributeMultiprocessorCount,
                                         dev) == hipSuccess) &&
                  (hipOccupancyMaxActiveBlocksPerMultiprocessor(
                       &maxBlk, persist3_kernel, 512, 0) == hipSuccess) &&
                  ((long long)maxBlk * cus >= (long long)NBLK);

    if (coopOK) {
        void* args[] = {(void*)&xh, (void*)&sq, (void*)&minEdge,
                        (void*)&lossAcc, (void*)&counters, (void*)&out};
        hipLaunchCooperativeKernel(reinterpret_cast<void*>(persist3_kernel),
                                   dim3(4, 8, NCLS), dim3(512), args, 0, stream);
    } else {
        for (int r = 0; r < NROUNDS; ++r) {
            scanmerge_kernel<<<dim3(4, NPT / 128, NCLS), 256, 0, stream>>>(
                xh, sq, comp, minEdge, lossAcc, done, counters, r);
        }
        final2_kernel<<<1, 64, 0, stream>>>(lossAcc, out);
    }
}

// Round 14
// 112.310 us; speedup vs baseline: 1.7376x; 1.0389x over previous
//
#include <hip/hip_runtime.h>

#define NCLS 8
#define NPT  2048
#define DIM  64
#define NROUNDS 11
#define NBLK 256                    // 4 cs * 8 rb * NCLS persistent blocks
#define CBLK 32                     // blocks per class
#define FINF 3.402823466e38f
#define INFK 0xFFFFFFFFu
#define INF64 0xFFFFFFFFFFFFFFFFull

// counters layout (u32): [c*32 + rnd] per-class barriers (8 x 32 = 256),
// [256] finish ticket, [257 ..) fallback tickets.
#define CTR_FIN      256
#define CTR_FALLBACK 257
#define NCNT         (CTR_FALLBACK + NROUNDS * NCLS)

typedef unsigned int u32;
typedef unsigned long long u64;
typedef unsigned short u16;
typedef _Float16 f16_t;
typedef __attribute__((ext_vector_type(8))) f16_t f16x8;
typedef __attribute__((ext_vector_type(4))) float f32x4;
typedef __attribute__((ext_vector_type(4))) u32 u32x4;

#define MFMAH(a, b, c) __builtin_amdgcn_mfma_f32_16x16x32_f16((a), (b), (c), 0, 0, 0)

#define ALOAD_U64(p) __hip_atomic_load((p), __ATOMIC_RELAXED, __HIP_MEMORY_SCOPE_AGENT)
#define ALOAD_U32(p) __hip_atomic_load((p), __ATOMIC_RELAXED, __HIP_MEMORY_SCOPE_AGENT)
#define ALOAD_F32(p) __hip_atomic_load((p), __ATOMIC_RELAXED, __HIP_MEMORY_SCOPE_AGENT)
#define ASTORE_F32(p, v) __hip_atomic_store((p), (v), __ATOMIC_RELAXED, __HIP_MEMORY_SCOPE_AGENT)

// ---------------------------------------------------------------------------
// Per-CLASS atomic barrier (proven rounds 12/13). Leading __syncthreads
// drains every wave's vmcnt -> this block's global atomicMins complete
// before the arrive. One counter per (class, round). Cooperative launch.
// ---------------------------------------------------------------------------
__device__ __forceinline__ void cbar(u32* __restrict__ ctr, int c, int inst) {
    __syncthreads();
    if (threadIdx.x == 0) {
        u32* a = &ctr[c * 32 + inst];
        __hip_atomic_fetch_add(a, 1u, __ATOMIC_RELAXED, __HIP_MEMORY_SCOPE_AGENT);
        while (ALOAD_U32(a) < CBLK) __builtin_amdgcn_s_sleep(1);
    }
    __syncthreads();
}

// ---------------------------------------------------------------------------
// Kernel 1: fp32 -> fp16 convert + exact fp32 row norms + ALL state init.
// ---------------------------------------------------------------------------
__global__ void convinit_kernel(const float* __restrict__ x, u16* __restrict__ xh,
                                float* __restrict__ sq, u32* __restrict__ comp,
                                u64* __restrict__ minEdge, float* __restrict__ lossAcc,
                                u32* __restrict__ done, u32* __restrict__ counters) {
    int row  = blockIdx.x * 4 + (threadIdx.x >> 6);
    int lane = threadIdx.x & 63;
    size_t idx = (size_t)row * DIM + lane;
    float v = x[idx];
    xh[idx] = __builtin_bit_cast(u16, (f16_t)v);   // RNE
    float s = v * v;
    #pragma unroll
    for (int m = 32; m >= 1; m >>= 1) s += __shfl_xor(s, m);
    if (lane == 0) {
        sq[row]   = s;
        comp[row] = (u32)(row & (NPT - 1));        // fallback path state
        if (row < NCLS) { lossAcc[row] = 0.0f; done[row] = 0u; }
    }
    int g = blockIdx.x * 256 + threadIdx.x;
    if (g < 2 * NCLS * NPT) minEdge[g] = INF64;    // both round-parity buffers
    if (g < NCNT) counters[g] = 0u;
}

// ---------------------------------------------------------------------------
// Kernel 2 (primary): persistent cooperative Boruvka, 512-thread blocks.
// Round-14 trims:
//  (1) 2-cycle safety pass REMOVED — provably dead: keys are unique (embed
//      mn|mx) and totally ordered; around any hook cycle keys are
//      non-increasing -> all equal -> same edge -> cycle length 2 = the
//      mutual pair, already broken by the L>O dedup.
//  (2) fmaxf(d2,0) REMOVED — a negative d2 has its sign bit set, so the
//      packed u32 key >= 0x80000000 and loses every min: identical
//      selection semantics, one less VALU op per element.
//  (3) Ping-pong pointer jumping: 1 barrier per doubling instead of 2.
// Everything else carried verified: single-pass fp16 MFMA Gram (bitwise-
// symmetric -> exact mutual dedup), decreasing round tags + parity buffers,
// LDS per-comp pre-reduction, per-class barriers, atomics-only, no fences.
// ---------------------------------------------------------------------------
__global__ __launch_bounds__(512) void persist4_kernel(
    const u16* __restrict__ xh, const float* __restrict__ sq,
    u64* __restrict__ minEdge, float* __restrict__ lossAcc,
    u32* __restrict__ counters, float* __restrict__ out)
{
    __shared__ u16   compL[NPT];                          // 4 KB persistent
    __shared__ float sqC[512];                            // 2 KB persistent
    __shared__ __align__(16) char uni[NPT * 8];           // 16 KB: minT | edgeL
    __shared__ u32   parentA[NPT];                        // 8 KB jump ping
    __shared__ u32   parentB[NPT];                        // 8 KB jump pong
    __shared__ float rwS[8];
    __shared__ u32   rcS[8];
    __shared__ u32   shChgA[16];
    __shared__ u32   shRoot, shConv;

    u64* minT  = (u64*)uni;               // scan:  per-component table
    u64* edgeL = (u64*)uni;               // merge: edge copy (same region)

    const int c    = blockIdx.z;
    const int rb   = blockIdx.y;          // row block (256 rows)
    const int cs   = blockIdx.x;          // col split (512 cols)
    const int tid  = threadIdx.x;
    const int lane = tid & 63;
    const int w    = tid >> 6;            // 8 waves
    const bool leader = (rb == 0 && cs == 0);

    const size_t xbase = (size_t)c * NPT * DIM;
    sqC[tid & 511] = sq[(size_t)c * NPT + cs * 512 + (tid & 511)];
    #pragma unroll
    for (int k = 0; k < 4; ++k) compL[k * 512 + tid] = (u16)(k * 512 + tid);

    const int kq   = (lane >> 4) * 8;
    const int arow = rb * 256 + w * 32 + (lane & 15);
    f16x8 Ah[2][2];
    #pragma unroll
    for (int rt = 0; rt < 2; ++rt)
        #pragma unroll
        for (int kk = 0; kk < 2; ++kk) {
            size_t off = xbase + (size_t)(arow + rt * 16) * DIM + kk * 32 + kq;
            Ah[rt][kk] = __builtin_bit_cast(f16x8, *(const u32x4*)(xh + off));
        }
    int   rowg_[2][4];
    float sqrow[2][4];
    #pragma unroll
    for (int rt = 0; rt < 2; ++rt)
        #pragma unroll
        for (int r = 0; r < 4; ++r) {
            int rg = rb * 256 + w * 32 + rt * 16 + ((lane >> 4) << 2) + r;
            rowg_[rt][r] = rg;
            sqrow[rt][r] = sq[(size_t)c * NPT + rg];
        }

    float classLoss = 0.0f;
    __syncthreads();

    for (int rnd = 0; rnd < NROUNDS; ++rnd) {
        u64* edgeGb = minEdge + ((size_t)(rnd & 1) * NCLS + c) * NPT;

        // --- scan ---
        #pragma unroll
        for (int k = 0; k < 4; ++k) minT[k * 512 + tid] = INF64;
        __syncthreads();

        u32 crow[2][4];
        #pragma unroll
        for (int rt = 0; rt < 2; ++rt)
            #pragma unroll
            for (int r = 0; r < 4; ++r) crow[rt][r] = compL[rowg_[rt][r]];

        u32 rm[2][4];
        #pragma unroll
        for (int rt = 0; rt < 2; ++rt)
            #pragma unroll
            for (int r = 0; r < 4; ++r) rm[rt][r] = INFK;

        #pragma unroll 8
        for (int ct = 0; ct < 32; ++ct) {
            const int colb = cs * 512 + ct * 16 + (lane & 15);
            f16x8 Bh[2];
            #pragma unroll
            for (int kk = 0; kk < 2; ++kk) {
                size_t off = xbase + (size_t)colb * DIM + kk * 32 + kq;
                Bh[kk] = __builtin_bit_cast(f16x8, *(const u32x4*)(xh + off));
            }
            u32   ccol = compL[colb];
            float sqc_ = sqC[ct * 16 + (lane & 15)];

            #pragma unroll
            for (int rt = 0; rt < 2; ++rt) {
                f32x4 acc = {0.f, 0.f, 0.f, 0.f};
                acc = MFMAH(Ah[rt][0], Bh[0], acc);
                acc = MFMAH(Ah[rt][1], Bh[1], acc);
                #pragma unroll
                for (int r = 0; r < 4; ++r) {
                    float d2 = fmaf(-2.0f, acc[r], sqrow[rt][r] + sqc_);
                    u32 bk = (__float_as_uint(d2) + 0x400u) & 0xFFFFF800u;  // RNE 21-bit
                    u32 k2 = bk | (u32)colb;
                    k2 = (crow[rt][r] == ccol) ? INFK : k2;   // masks self too
                    rm[rt][r] = min(rm[rt][r], k2);
                }
            }
        }

        const u64 tagbits = (u64)(15 - rnd) << 60;   // decreasing: new wins
        #pragma unroll
        for (int rt = 0; rt < 2; ++rt)
            #pragma unroll
            for (int r = 0; r < 4; ++r) {
                u32 bv = rm[rt][r];
                #pragma unroll
                for (int m = 8; m >= 1; m >>= 1)
                    bv = min(bv, (u32)__shfl_xor((int)bv, m));
                if ((lane & 15) == 0 && bv != INFK) {
                    int rowg = rowg_[rt][r];
                    int colg = (int)(bv & 0x7FFu);
                    u32 d21  = bv >> 11;
                    int mn = rowg < colg ? rowg : colg;
                    int mx = rowg < colg ? colg : rowg;
                    u64 key = tagbits | ((u64)d21 << 22) | ((u64)mn << 11) | (u64)mx;
                    atomicMin(&minT[crow[rt][r]], key);
                }
            }
        __syncthreads();

        #pragma unroll
        for (int k = 0; k < 4; ++k) {
            int i = k * 512 + tid;
            u64 e = minT[i];
            if (e != INF64) atomicMin(&edgeGb[i], e);
        }

        cbar(counters, c, rnd);   // leading syncthreads drains our atomicMins

        // --- merge (redundant, identical in all 32 blocks of class c) ---
        #pragma unroll
        for (int k = 0; k < 4; ++k) {
            int i = k * 512 + tid;
            edgeL[i]   = ALOAD_U64(&edgeGb[i]);
            parentA[i] = (u32)i;
        }
        if (tid < 16) shChgA[tid] = 0u;
        __syncthreads();

        const u64 T = (u64)(15 - rnd);
        float myw = 0.0f;
        u32   mycnt = 0;
        #pragma unroll
        for (int k = 0; k < 4; ++k) {
            int L = k * 512 + tid;
            u64 e = edgeL[L];
            if (e != INF64 && (e >> 60) == T) {
                int mn = (int)((e >> 11) & 0x7FF);
                int mx = (int)(e & 0x7FF);
                u32 A = compL[mn], B = compL[mx];
                u32 O = (A == (u32)L) ? B : A;
                bool mutual = (edgeL[O] == e);
                if (!(mutual && (u32)L > O)) {
                    parentA[L] = O;
                    float d2 = __uint_as_float(((u32)(e >> 22) & 0x1FFFFFu) << 11);
                    myw += fabsf(sqrtf(d2) - 1.0f);
                    ++mycnt;
                }
            }
        }
        __syncthreads();

        // ping-pong pointer jumping: 1 barrier per doubling. Cap 14 (11
        // doublings cover depth 2048 + 1 detect + margin).
        u32* pc = parentA;
        u32* pn = parentB;
        for (int itj = 0; itj < 14; ++itj) {
            u32 np[4]; u32 ch = 0;
            #pragma unroll
            for (int k = 0; k < 4; ++k) {
                u32 p  = pc[k * 512 + tid];
                u32 pp = pc[p];
                np[k] = pp;
                ch |= (u32)(pp != p);
            }
            if (ch) shChgA[itj & 15] = 1u;   // benign race: all writers write 1
            #pragma unroll
            for (int k = 0; k < 4; ++k) pn[k * 512 + tid] = np[k];
            __syncthreads();
            u32* t = pc; pc = pn; pn = t;
            if (shChgA[itj & 15] == 0u) break;
        }

        // new comp (LDS only) + convergence + loss reduction
        u16 nc[4];
        #pragma unroll
        for (int k = 0; k < 4; ++k) nc[k] = (u16)pc[compL[k * 512 + tid]];
        if (tid == 0) { shRoot = nc[0]; shConv = 1; }
        __syncthreads();
        u32 bad = 0;
        #pragma unroll
        for (int k = 0; k < 4; ++k) {
            compL[k * 512 + tid] = nc[k];
            bad |= (u32)(nc[k] != (u16)shRoot);
        }
        if (bad) shConv = 0;   // benign race: all writers write 0

        #pragma unroll
        for (int m = 32; m >= 1; m >>= 1) {
            myw   += __shfl_xor(myw, m);
            mycnt += (u32)__shfl_xor((int)mycnt, m);
        }
        if (lane == 0) { rwS[w] = myw; rcS[w] = mycnt; }
        __syncthreads();

        float rwTot = 0.0f; u32 rcTot = 0u;
        #pragma unroll
        for (int i = 0; i < 8; ++i) { rwTot += rwS[i]; rcTot += rcS[i]; }
        classLoss += rwTot;
        if (shConv != 0u || rcTot == 0u) break;   // identical in all 32 blocks
    }

    // ---- finish: leader publishes loss; 8th finisher sums (fixed order) ----
    if (leader && tid == 0) ASTORE_F32(&lossAcc[c], classLoss);
    __syncthreads();            // drains the ASTORE before the ticket
    if (leader && tid == 0) {
        u32 t = __hip_atomic_fetch_add(&counters[CTR_FIN], 1u,
                                       __ATOMIC_RELAXED, __HIP_MEMORY_SCOPE_AGENT);
        if (t == NCLS - 1) {
            float s = 0.0f;
            for (int cc = 0; cc < NCLS; ++cc) s += ALOAD_F32(&lossAcc[cc]);
            out[0] = s * (1.0f / (float)(NPT - 1));
        }
    }
}

// ===========================================================================
// Fallback path: proven round-10 pipeline (149 us) — used if the cooperative
// co-residency check fails.
// ===========================================================================
__global__ __launch_bounds__(256) void scanmerge_kernel(
    const u16* __restrict__ xh, const float* __restrict__ sq,
    u32* __restrict__ comp, u64* __restrict__ minEdge,
    float* __restrict__ lossAcc, u32* __restrict__ classDone,
    u32* __restrict__ counters, int rnd)
{
    const int c = blockIdx.z;
    if (classDone[c]) return;
    const int cs   = blockIdx.x;
    const int rb   = blockIdx.y;
    const int tid  = threadIdx.x;
    const int lane = tid & 63;
    const int w    = tid >> 6;

    __shared__ u32 compL[NPT];
    __shared__ __align__(16) char bufA[NPT * 4];
    __shared__ __align__(16) char bufB[NPT * 8];
    __shared__ float rw[256];
    __shared__ u32   rc[256];
    __shared__ u32   shTicket;
    __shared__ int   conv;

    float* sqL  = (float*)bufA;
    u64*   minT = (u64*)bufB;

    const u32*   compG = comp + (size_t)c * NPT;
    const float* sqG   = sq + (size_t)c * NPT;
    u64*         edgeG = minEdge + (size_t)c * NPT;

    #pragma unroll
    for (int k = 0; k < NPT / 256; ++k) {
        int i = k * 256 + tid;
        compL[i] = compG[i];
        sqL[i]   = sqG[i];
        minT[i]  = INF64;
    }
    __syncthreads();

    const size_t xbase = (size_t)c * NPT * DIM;
    const int    kq    = (lane >> 4) * 8;
    const int    arow  = rb * 128 + w * 32 + (lane & 15);

    f16x8 Ah[2][2];
    #pragma unroll
    for (int rt = 0; rt < 2; ++rt)
        #pragma unroll
        for (int kk = 0; kk < 2; ++kk) {
            size_t off = xbase + (size_t)(arow + rt * 16) * DIM + kk * 32 + kq;
            Ah[rt][kk] = __builtin_bit_cast(f16x8, *(const u32x4*)(xh + off));
        }

    int   rowg_[2][4];
    float sqrow[2][4];
    u32   crow[2][4];
    #pragma unroll
    for (int rt = 0; rt < 2; ++rt)
        #pragma unroll
        for (int r = 0; r < 4; ++r) {
            int rg = rb * 128 + w * 32 + rt * 16 + ((lane >> 4) << 2) + r;
            rowg_[rt][r] = rg;
            sqrow[rt][r] = sqL[rg];
            crow[rt][r]  = compL[rg];
        }

    u32 rm[2][4];
    #pragma unroll
    for (int rt = 0; rt < 2; ++rt)
        #pragma unroll
        for (int r = 0; r < 4; ++r) rm[rt][r] = INFK;

    #pragma unroll 2
    for (int ct = 0; ct < 32; ++ct) {
        const int colb = cs * 512 + ct * 16 + (lane & 15);
        f16x8 Bh[2];
        #pragma unroll
        for (int kk = 0; kk < 2; ++kk) {
            size_t off = xbase + (size_t)colb * DIM + kk * 32 + kq;
            Bh[kk] = __builtin_bit_cast(f16x8, *(const u32x4*)(xh + off));
        }
        u32   ccol = compL[colb];
        float sqc_ = sqL[colb];

        #pragma unroll
        for (int rt = 0; rt < 2; ++rt) {
            f32x4 acc = {0.f, 0.f, 0.f, 0.f};
            acc = MFMAH(Ah[rt][0], Bh[0], acc);
            acc = MFMAH(Ah[rt][1], Bh[1], acc);
            #pragma unroll
            for (int r = 0; r < 4; ++r) {
                float d2 = fmaf(-2.0f, acc[r], sqrow[rt][r] + sqc_);
                d2 = fmaxf(d2, 0.0f);
                u32 bk = (__float_as_uint(d2) + 0x400u) & 0xFFFFF800u;
                u32 k2 = bk | (u32)colb;
                k2 = (crow[rt][r] == ccol) ? INFK : k2;
                rm[rt][r] = min(rm[rt][r], k2);
            }
        }
    }

    #pragma unroll
    for (int rt = 0; rt < 2; ++rt)
        #pragma unroll
        for (int r = 0; r < 4; ++r) {
            u32 bv = rm[rt][r];
            #pragma unroll
            for (int m = 8; m >= 1; m >>= 1)
                bv = min(bv, (u32)__shfl_xor((int)bv, m));
            if ((lane & 15) == 0 && bv != INFK) {
                int rowg = rowg_[rt][r];
                int colg = (int)(bv & 0x7FFu);
                u32 d21  = bv >> 11;
                int mn = rowg < colg ? rowg : colg;
                int mx = rowg < colg ? colg : rowg;
                u64 key = ((u64)d21 << 22) | ((u64)mn << 11) | (u64)mx;
                atomicMin(&minT[crow[rt][r]], key);
            }
        }
    __syncthreads();

    #pragma unroll
    for (int k = 0; k < NPT / 256; ++k) {
        int i = k * 256 + tid;
        u64 e = minT[i];
        if (e != INF64) atomicMin(&edgeG[i], e);
    }

    __syncthreads();
    if (tid == 0)
        shTicket = __hip_atomic_fetch_add(&counters[CTR_FALLBACK + rnd * NCLS + c], 1u,
                                          __ATOMIC_RELAXED, __HIP_MEMORY_SCOPE_AGENT);
    __syncthreads();
    if (shTicket != 63u) return;

    u32* parentL = (u32*)bufA;
    u64* edgeL   = (u64*)bufB;
    u32* compGm  = comp + (size_t)c * NPT;

    #pragma unroll
    for (int k = 0; k < NPT / 256; ++k) {
        int i = k * 256 + tid;
        edgeL[i]   = ALOAD_U64(&edgeG[i]);
        parentL[i] = (u32)i;
    }
    if (tid == 0) conv = 1;
    __syncthreads();

    float myw = 0.0f;
    int   mycnt = 0;
    #pragma unroll
    for (int k = 0; k < NPT / 256; ++k) {
        int L = k * 256 + tid;
        u64 e = edgeL[L];
        if (e != INF64) {
            int mn = (int)((e >> 11) & 0x7FF);
            int mx = (int)(e & 0x7FF);
            u32 A = compL[mn], B = compL[mx];
            u32 O = (A == (u32)L) ? B : A;
            bool mutual = (edgeL[O] == e);
            if (!(mutual && (u32)L > O)) {
                parentL[L] = O;
                float d2 = __uint_as_float((u32)(e >> 22) << 11);
                myw += fabsf(sqrtf(d2) - 1.0f);
                mycnt += 1;
            }
        }
    }
    __syncthreads();

    #pragma unroll
    for (int k = 0; k < NPT / 256; ++k) {
        int L = k * 256 + tid;
        u32 p1 = parentL[L];
        if (p1 != (u32)L && parentL[p1] == (u32)L && (u32)L > p1) parentL[L] = (u32)L;
    }
    __syncthreads();

    for (int it = 0; it < 11; ++it) {
        u32 np[NPT / 256];
        #pragma unroll
        for (int k = 0; k < NPT / 256; ++k) {
            int L = k * 256 + tid;
            np[k] = parentL[parentL[L]];
        }
        __syncthreads();
        #pragma unroll
        for (int k = 0; k < NPT / 256; ++k) parentL[k * 256 + tid] = np[k];
        __syncthreads();
    }

    u32 root0 = parentL[compL[0]];
    #pragma unroll
    for (int k = 0; k < NPT / 256; ++k) {
        int v = k * 256 + tid;
        u32 nc = parentL[compL[v]];
        compGm[v] = nc;
        if (nc != root0) conv = 0;
        edgeG[v] = INF64;
    }

    rw[tid] = myw; rc[tid] = (u32)mycnt;
    __syncthreads();
    for (int s = 128; s >= 1; s >>= 1) {
        if (tid < s) { rw[tid] += rw[tid + s]; rc[tid] += rc[tid + s]; }
        __syncthreads();
    }
    if (tid == 0) {
        lossAcc[c] += rw[0];
        if (conv || rc[0] == 0u) classDone[c] = 1u;
    }
}

__global__ void final2_kernel(const float* __restrict__ lossAcc, float* __restrict__ out) {
    if (threadIdx.x == 0 && blockIdx.x == 0) {
        float s = 0.0f;
        for (int cc = 0; cc < NCLS; ++cc) s += lossAcc[cc] * (1.0f / (float)(NPT - 1));
        out[0] = s;
    }
}

extern "C" void kernel_launch(void* const* d_in, const int* in_sizes, int n_in,
                              void* d_out, int out_size, void* d_ws, size_t ws_size,
                              hipStream_t stream) {
    const float* x   = (const float*)d_in[0];
    float*       out = (float*)d_out;

    const size_t nv = (size_t)NCLS * NPT;
    const size_t nx = (size_t)NCLS * NPT * DIM;

    const size_t off_me   = 0;                                  // 2 bufs, u64
    const size_t off_sq   = off_me + 2 * nv * sizeof(u64);
    const size_t off_comp = off_sq + nv * sizeof(float);
    const size_t off_loss = off_comp + nv * sizeof(u32);
    const size_t off_done = off_loss + NCLS * sizeof(float);
    const size_t off_cnt  = off_done + NCLS * sizeof(u32);
    const size_t off_xh   = off_cnt + (((size_t)NCNT + 7) & ~7ull) * sizeof(u32);
    const size_t need     = off_xh + nx * sizeof(u16);

    if (ws_size < need) return;   // ws is known-large in this harness

    u64*   minEdge  = (u64*)((char*)d_ws + off_me);
    float* sq       = (float*)((char*)d_ws + off_sq);
    u32*   comp     = (u32*)((char*)d_ws + off_comp);
    float* lossAcc  = (float*)((char*)d_ws + off_loss);
    u32*   done     = (u32*)((char*)d_ws + off_done);
    u32*   counters = (u32*)((char*)d_ws + off_cnt);
    u16*   xh       = (u16*)((char*)d_ws + off_xh);

    convinit_kernel<<<(NCLS * NPT) / 4, 256, 0, stream>>>(x, xh, sq, comp,
                                                          minEdge, lossAcc, done,
                                                          counters);

    // Host-side (capture-safe, deterministic) co-residency check — round-6
    // lesson: never coop-launch blind.
    int dev = 0, cus = 0, maxBlk = 0;
    bool coopOK = (hipGetDevice(&dev) == hipSuccess) &&
                  (hipDeviceGetAttribute(&cus, hipDeviceAttributeMultiprocessorCount,
                                         dev) == hipSuccess) &&
                  (hipOccupancyMaxActiveBlocksPerMultiprocessor(
                       &maxBlk, persist4_kernel, 512, 0) == hipSuccess) &&
                  ((long long)maxBlk * cus >= (long long)NBLK);

    if (coopOK) {
        void* args[] = {(void*)&xh, (void*)&sq, (void*)&minEdge,
                        (void*)&lossAcc, (void*)&counters, (void*)&out};
        hipLaunchCooperativeKernel(reinterpret_cast<void*>(persist4_kernel),
                                   dim3(4, 8, NCLS), dim3(512), args, 0, stream);
    } else {
        for (int r = 0; r < NROUNDS; ++r) {
            scanmerge_kernel<<<dim3(4, NPT / 128, NCLS), 256, 0, stream>>>(
                xh, sq, comp, minEdge, lossAcc, done, counters, r);
        }
        final2_kernel<<<1, 64, 0, stream>>>(lossAcc, out);
    }
}